// Round 12
// baseline (495.142 us; speedup 1.0000x reference)
//
#include <hip/hip_runtime.h>
#include <hip/hip_fp16.h>
#include <math.h>

#define N_NODES 50000
#define E_EDGES 800000
#define ET (E_EDGES + N_NODES)   // edges + self loops
#define L_LAYERS 4
#define NB_SCAN ((N_NODES + 255) / 256)   // 196
#define MF_BLOCKS ((N_NODES + 63) / 64)   // 782 (64 rows per block)
#define WAVE_BLOCKS ((N_NODES * 64 + 255) / 256)  // 12500

typedef __attribute__((ext_vector_type(8))) short short8;
typedef __attribute__((ext_vector_type(4))) float f32x4;

// gelu(x) = 0.5x(1+erf(x/sqrt2)); erf via A&S 7.1.26, |err| <= 1.5e-7.
__device__ __forceinline__ float gelu_f(float x) {
    float z = fabsf(x) * 0.70710678118654752f;
    float t = __fdividef(1.0f, fmaf(0.3275911f, z, 1.0f));
    float p = t * fmaf(t, fmaf(t, fmaf(t, fmaf(t, 1.061405429f, -1.453152027f),
                                       1.421413741f), -0.284496736f),
                       0.254829592f);
    float e = __expf(-z * z);
    float erfz = copysignf(fmaf(-p, e, 1.0f), x);
    return 0.5f * x * (1.0f + erfz);
}

__device__ __forceinline__ void split_hl(float x, unsigned short& h, unsigned short& lo) {
    unsigned u = __float_as_uint(x);
    h = (unsigned short)(u >> 16);
    float hif = __uint_as_float(u & 0xffff0000u);
    lo = (unsigned short)(__float_as_uint(x - hif) >> 16);
}

// 8 fp16 (one 16B load) fused convert+scale+accumulate into 8 f32 accs.
// fmaf(fpext(h), m, acc) folds to v_fma_mix_f32 (exact f32 fma).
__device__ __forceinline__ void fma8h(const float4& raw, float m, float* acc) {
    const __half2* h = reinterpret_cast<const __half2*>(&raw);
#pragma unroll
    for (int i = 0; i < 4; ++i) {
        float2 f = __half22float2(h[i]);
        acc[2 * i]     = fmaf(f.x, m, acc[2 * i]);
        acc[2 * i + 1] = fmaf(f.y, m, acc[2 * i + 1]);
    }
}

// ---------------- graph preprocessing ----------------

__global__ __launch_bounds__(256) void count_pos(const int* __restrict__ ecol,
                                                 int* __restrict__ cnt,
                                                 int* __restrict__ aux) {
    int e = blockIdx.x * 256 + threadIdx.x;
    if (e >= ET) return;
    int c = (e < E_EDGES) ? ecol[e] : (e - E_EDGES);
    aux[e] = atomicAdd(&cnt[c], 1);
}

__global__ __launch_bounds__(256) void scan_part1(const int* __restrict__ cnt,
                                                  int* __restrict__ bsum) {
    __shared__ int red[256];
    int t = threadIdx.x;
    int i = blockIdx.x * 256 + t;
    red[t] = (i < N_NODES) ? cnt[i] : 0;
    __syncthreads();
#pragma unroll
    for (int off = 128; off; off >>= 1) {
        if (t < off) red[t] += red[t + off];
        __syncthreads();
    }
    if (t == 0) bsum[blockIdx.x] = red[0];
}

// scan_part3 with scan_part2 folded in: per-block reduce of preceding bsum
// entries (raw block sums; NB_SCAN=196 < 256) gives this block's base.
__global__ __launch_bounds__(256) void scan_part3(const int* __restrict__ cnt,
                                                  const int* __restrict__ bsum,
                                                  int* __restrict__ ptrb,
                                                  float* __restrict__ dinv) {
    __shared__ int red[256];
    __shared__ int sh[256];
    int t = threadIdx.x;
    // base = sum of bsum[j] for j < blockIdx.x
    red[t] = (t < (int)blockIdx.x) ? bsum[t] : 0;
    __syncthreads();
#pragma unroll
    for (int off = 128; off; off >>= 1) {
        if (t < off) red[t] += red[t + off];
        __syncthreads();
    }
    int base = red[0];
    int i = blockIdx.x * 256 + t;
    int v = (i < N_NODES) ? cnt[i] : 0;
    sh[t] = v;
    __syncthreads();
    for (int off = 1; off < 256; off <<= 1) {
        int u = (t >= off) ? sh[t - off] : 0;
        __syncthreads();
        sh[t] += u;
        __syncthreads();
    }
    int excl = sh[t] - v + base;
    if (i < N_NODES) {
        ptrb[i] = excl;
        dinv[i] = rsqrtf((float)v);   // deg >= 1 (self loop)
    }
    if (i == N_NODES - 1) ptrb[N_NODES] = excl + v;
}

// separable norm: only src index needed per edge (dinv folded into tables/out)
__global__ __launch_bounds__(256) void bucket(const int* __restrict__ erow,
                                              const int* __restrict__ ecol,
                                              const int* __restrict__ aux,
                                              const int* __restrict__ ptrb,
                                              int* __restrict__ eidx) {
    int e = blockIdx.x * 256 + threadIdx.x;
    if (e >= ET) return;
    int r, c;
    if (e < E_EDGES) { r = erow[e]; c = ecol[e]; }
    else             { r = e - E_EDGES; c = r; }
    int pos = ptrb[c] + aux[e];
    eidx[pos] = r;
}

// ---------------- W pre-layout: hi/lo bf16 in B-fragment lane order ----------------
// Fragment: B[k = q*8+j][n], lane = q*16+n. Storage [layer][s][nt][lane][j], 16B/lane.
// gcn: s=0..3 (K=128), nt=0..7 (N=128).  gna: s=0..1 (K=64), nt=0..7 (w1 cols|w2 cols).
// Per s-step the hi (and lo) block is 8 nt x 64 lanes x 8 shorts = 8 KB contiguous.

__global__ __launch_bounds__(256) void prep_w(const float* __restrict__ gcn_W,
                                              const float* __restrict__ w1W,
                                              const float* __restrict__ w2W,
                                              unsigned short* __restrict__ gf_hi,
                                              unsigned short* __restrict__ gf_lo,
                                              unsigned short* __restrict__ nf_hi,
                                              unsigned short* __restrict__ nf_lo) {
    int idx = blockIdx.x * 256 + threadIdx.x;
    if (idx < 8192) {                       // gcn: 4 layer x 4 s x 8 nt x 64 lane
        int lane = idx & 63, nt = (idx >> 6) & 7, s = (idx >> 9) & 3, layer = idx >> 11;
        int q = lane >> 4, n = lane & 15;
        const float* W = gcn_W + (size_t)layer * 128 * 128;
        size_t o = (size_t)idx * 8;
#pragma unroll
        for (int j = 0; j < 8; ++j) {
            float x = W[(size_t)(s * 32 + q * 8 + j) * 128 + nt * 16 + n];
            unsigned short h, lo;
            split_hl(x, h, lo);
            gf_hi[o + j] = h; gf_lo[o + j] = lo;
        }
    } else if (idx < 8192 + 4096) {         // gna: 4 layer x 2 s x 8 nt x 64 lane
        int t = idx - 8192;
        int lane = t & 63, nt = (t >> 6) & 7, s = (t >> 9) & 1, layer = t >> 10;
        int q = lane >> 4, n = lane & 15;
        int col = nt * 16 + n;              // <64 -> w1, >=64 -> w2
        const float* W = (col < 64) ? (w1W + (size_t)layer * 64 * 64)
                                    : (w2W + (size_t)layer * 64 * 64);
        int c = col & 63;
        size_t o = (size_t)t * 8;
#pragma unroll
        for (int j = 0; j < 8; ++j) {
            float x = W[(size_t)(s * 32 + q * 8 + j) * 64 + c];
            unsigned short h, lo;
            split_hl(x, h, lo);
            nf_hi[o + j] = h; nf_lo[o + j] = lo;
        }
    }
}

// ---------------- MFMA GEMM, W staged fully in LDS up-front ---------------------
// R8 counters showed the GEMM latency-bound (MfmaUtil 5.9%, VALUBusy 9.7%, HBM
// 15%, occ 25%): each wave serially ate the latency of its 64 global W-fragment
// loads. Fix (boring version): the whole W operand (GCN 64 KB, GNA 32 KB) is
// block-uniform — copy it into LDS once per block with a plain unrolled
// 256-thread copy loop, one barrier, then feed MFMAs with ds_read_b128.

__global__ __launch_bounds__(256) void gemm_both(
    const float* __restrict__ A0, const float* __restrict__ A1,
    const unsigned short* __restrict__ gfh, const unsigned short* __restrict__ gfl,
    const unsigned short* __restrict__ nfh, const unsigned short* __restrict__ nfl,
    const float* __restrict__ b1, const float* __restrict__ b2,
    const float* __restrict__ avec, const float* __restrict__ dinv,
    __half* __restrict__ h2, float* __restrict__ baseb,
    __half* __restrict__ ut, float* __restrict__ ub) {
    __shared__ uint4 lbuf[4096];   // 64 KB: [0..2047] hi (nsteps x 512), [2048..4095] lo
    int tid = threadIdx.x;
    int w  = tid >> 6;
    int l  = tid & 63;
    int lq = l >> 4;
    int ln = l & 15;
    bool isg = blockIdx.x >= MF_BLOCKS;
    int blk = isg ? (blockIdx.x - MF_BLOCKS) : blockIdx.x;
    int m0 = blk * 64;
    int arow = m0 + w * 16 + ln;
    bool avalid = arow < N_NODES;
    const float* A = isg ? A1 : A0;
    const unsigned short* wfh = isg ? nfh : gfh;
    const unsigned short* wfl = isg ? nfl : gfl;
    const int Kfull  = isg ? 64 : 128;
    const int nsteps = isg ? 2 : 4;

    // stage all W fragments (hi+lo) into LDS; uniform-predicate unrolled copy
    {
        const uint4* gh = (const uint4*)wfh;
        const uint4* gl = (const uint4*)wfl;
        int nf = nsteps * 512;              // 2048 (gcn) or 1024 (gna)
#pragma unroll
        for (int i = 0; i < 8; ++i) {
            int idx = tid + i * 256;
            if (idx < nf) {
                lbuf[idx]        = gh[idx];
                lbuf[2048 + idx] = gl[idx];
            }
        }
    }
    __syncthreads();

    f32x4 acc[8];
#pragma unroll
    for (int i = 0; i < 8; ++i) acc[i] = (f32x4){0.f, 0.f, 0.f, 0.f};

    for (int s = 0; s < nsteps; ++s) {
        // A fragment (global, per-row)
        float4 a0 = make_float4(0.f, 0.f, 0.f, 0.f);
        float4 a1 = make_float4(0.f, 0.f, 0.f, 0.f);
        if (avalid) {
            const float* ap = A + (size_t)arow * Kfull + s * 32 + lq * 8;
            a0 = *(const float4*)ap;
            a1 = *(const float4*)(ap + 4);
        }
        float xs[8] = {a0.x, a0.y, a0.z, a0.w, a1.x, a1.y, a1.z, a1.w};
        short8 ah, al;
#pragma unroll
        for (int c = 0; c < 8; ++c) {
            unsigned short h, lo;
            split_hl(xs[c], h, lo);
            ah[c] = (short)h; al[c] = (short)lo;
        }
#pragma unroll
        for (int nt = 0; nt < 8; ++nt) {
            uint4 rh = lbuf[s * 512 + nt * 64 + l];
            uint4 rl = lbuf[2048 + s * 512 + nt * 64 + l];
            short8 wh = *(const short8*)&rh;
            short8 wl = *(const short8*)&rl;
            acc[nt] = __builtin_amdgcn_mfma_f32_16x16x32_bf16(ah, wh, acc[nt], 0, 0, 0);
            acc[nt] = __builtin_amdgcn_mfma_f32_16x16x32_bf16(ah, wl, acc[nt], 0, 0, 0);
            acc[nt] = __builtin_amdgcn_mfma_f32_16x16x32_bf16(al, wh, acc[nt], 0, 0, 0);
        }
    }

    // C layout: col = ln (per nt tile), row-in-tile = lq*4 + r (verified)
    if (!isg) {
        float dv[4];
#pragma unroll
        for (int r = 0; r < 4; ++r) {
            int row = m0 + w * 16 + lq * 4 + r;
            dv[r] = (row < N_NODES) ? dinv[row] : 0.f;
        }
#pragma unroll
        for (int nt = 0; nt < 8; ++nt) {
            int col = nt * 16 + ln;
#pragma unroll
            for (int r = 0; r < 4; ++r) {
                int row = m0 + w * 16 + lq * 4 + r;
                if (row < N_NODES)
                    h2[(size_t)row * 128 + col] = __float2half(acc[nt][r] * dv[r]);
            }
        }
    } else {
        // base = A1@W1 + b1
#pragma unroll
        for (int nt = 0; nt < 4; ++nt) {
            int col = nt * 16 + ln;
            float bb = b1[col];
#pragma unroll
            for (int r = 0; r < 4; ++r) {
                int row = m0 + w * 16 + lq * 4 + r;
                if (row < N_NODES) baseb[(size_t)row * 64 + col] = acc[nt][r] + bb;
            }
        }
        // t = A1@W2 + b2; ta = t @ avec (row-reduce over 16 lanes)
        float pa[4] = {0.f, 0.f, 0.f, 0.f};
        float t2s[4][4];
#pragma unroll
        for (int nt = 4; nt < 8; ++nt) {
            int col = (nt - 4) * 16 + ln;
            float bb = b2[col];
            float av = avec[col];
#pragma unroll
            for (int r = 0; r < 4; ++r) {
                float t2 = acc[nt][r] + bb;
                t2s[nt - 4][r] = t2;
                pa[r] += t2 * av;
            }
        }
#pragma unroll
        for (int r = 0; r < 4; ++r) {
            pa[r] += __shfl_xor(pa[r], 1);
            pa[r] += __shfl_xor(pa[r], 2);
            pa[r] += __shfl_xor(pa[r], 4);
            pa[r] += __shfl_xor(pa[r], 8);
        }
        float ur[4];
#pragma unroll
        for (int r = 0; r < 4; ++r) ur[r] = expf(-pa[r]);
        // ut = u * t (fp16)  and u per row (f32)
#pragma unroll
        for (int nt = 0; nt < 4; ++nt) {
            int col = nt * 16 + ln;
#pragma unroll
            for (int r = 0; r < 4; ++r) {
                int row = m0 + w * 16 + lq * 4 + r;
                if (row < N_NODES)
                    ut[(size_t)row * 64 + col] = __float2half(t2s[nt][r] * ur[r]);
            }
        }
        if (ln == 0) {
#pragma unroll
            for (int r = 0; r < 4; ++r) {
                int row = m0 + w * 16 + lq * 4 + r;
                if (row < N_NODES) ub[row] = ur[r];
            }
        }
    }
}

// ---------------- GCN edge aggregation (one wave per dst, single pass) ---------
// fp16 rows (256B), 16 lanes x 16B, 4 edge slots, chunked shfl-broadcast loop
// (R7-proven). Distributed epilogue: each sub handles 2 cols.

__global__ __launch_bounds__(256) void agg_gcn(const __half* __restrict__ h2,
                                               const int* __restrict__ ptrb,
                                               const int* __restrict__ eidx,
                                               const float* __restrict__ dinv,
                                               const float* __restrict__ bias,
                                               float* __restrict__ out,
                                               int apply_gelu) {
    int dst  = (blockIdx.x * 256 + threadIdx.x) >> 6;
    int lane = threadIdx.x & 63;
    if (dst >= N_NODES) return;
    int sub = lane >> 4;                  // 0..3 : edge slot
    int fl  = lane & 15;                  // 16 groups x 8 cols = 128
    int p0 = ptrb[dst], p1 = ptrb[dst + 1];
    float acc[8];
#pragma unroll
    for (int i = 0; i < 8; ++i) acc[i] = 0.f;
    for (int p = p0; p < p1; p += 64) {
        int nb = min(64, p1 - p);            // wave-uniform
        int srcs = (lane < nb) ? eidx[p + lane] : 0;
        for (int eb = 0; eb < nb; eb += 16) { // uniform trip count
            int   sv[4];
            float mk[4];
#pragma unroll
            for (int k = 0; k < 4; ++k) {
                int e = eb + sub + 4 * k;
                int c = min(e, nb - 1);
                sv[k] = __shfl(srcs, c);
                mk[k] = (e < nb) ? 1.f : 0.f;
            }
            float4 raw[4];
#pragma unroll
            for (int k = 0; k < 4; ++k)
                raw[k] = *(const float4*)(h2 + (size_t)sv[k] * 128 + fl * 8);
#pragma unroll
            for (int k = 0; k < 4; ++k) fma8h(raw[k], mk[k], acc);
        }
    }
#pragma unroll
    for (int off = 16; off <= 32; off <<= 1)
#pragma unroll
        for (int i = 0; i < 8; ++i) acc[i] += __shfl_xor(acc[i], off);
    // distributed epilogue: lane covers cols c0 = fl*8 + 2*sub .. +1
    {
        float dd = dinv[dst];
        int c0 = fl * 8 + 2 * sub;
        float2 bb = *(const float2*)(bias + c0);
        float v0 = fmaf(dd, acc[2 * sub], bb.x);
        float v1 = fmaf(dd, acc[2 * sub + 1], bb.y);
        if (apply_gelu) { v0 = gelu_f(v0); v1 = gelu_f(v1); }
        *(float2*)(out + (size_t)dst * 128 + c0) = make_float2(v0, v1);
    }
}

// ---------------- GNA edge aggregation (one wave per dst) ----------------
// ut rows fp16 (128B), 8 lanes x 16B, 8 edge slots, chunked shfl-broadcast loop
// (R7-proven). Distributed epilogue: each sub handles 1 col.

__global__ __launch_bounds__(256) void gna_agg(const __half* __restrict__ ut,
                                               const float* __restrict__ ub,
                                               const int* __restrict__ ptrb,
                                               const int* __restrict__ eidx,
                                               const float* __restrict__ base,
                                               float* __restrict__ gout) {
    int dst  = (blockIdx.x * 256 + threadIdx.x) >> 6;
    int lane = threadIdx.x & 63;
    if (dst >= N_NODES) return;
    int p0 = ptrb[dst], p1 = ptrb[dst + 1];
    int sub = lane >> 3;                  // 0..7 : edge slot
    int fl  = lane & 7;                   // 8 groups x 8 cols = 64
    float se = 0.f;
    float acc[8];
#pragma unroll
    for (int i = 0; i < 8; ++i) acc[i] = 0.f;
    for (int p = p0; p < p1; p += 64) {
        int nb = min(64, p1 - p);            // wave-uniform
        int srcs = (lane < nb) ? eidx[p + lane] : 0;
        if (lane < nb) se += ub[srcs];       // L2-hot 200 KB table
        for (int eb = 0; eb < nb; eb += 32) { // uniform trip count
            int   sv[4];
            float mk[4];
#pragma unroll
            for (int k = 0; k < 4; ++k) {
                int e = eb + sub + 8 * k;
                int c = min(e, nb - 1);
                sv[k] = __shfl(srcs, c);
                mk[k] = (e < nb) ? 1.f : 0.f;
            }
            float4 raw[4];
#pragma unroll
            for (int k = 0; k < 4; ++k)
                raw[k] = *(const float4*)(ut + (size_t)sv[k] * 64 + fl * 8);
#pragma unroll
            for (int k = 0; k < 4; ++k) fma8h(raw[k], mk[k], acc);
        }
    }
#pragma unroll
    for (int off = 1; off < 64; off <<= 1) se += __shfl_xor(se, off);
#pragma unroll
    for (int off = 8; off <= 32; off <<= 1)
#pragma unroll
        for (int i = 0; i < 8; ++i) acc[i] += __shfl_xor(acc[i], off);
    // distributed epilogue: lane covers col c0 = fl*8 + sub
    {
        float winv = __fdividef(1.0f, se + 1e-16f);
        int c0 = fl * 8 + sub;
        float bs = base[(size_t)dst * 64 + c0];
        gout[(size_t)dst * 64 + c0] = gelu_f(fmaf(acc[sub], winv, bs));
    }
}

// ---------------- launch ----------------

extern "C" void kernel_launch(void* const* d_in, const int* in_sizes, int n_in,
                              void* d_out, int out_size, void* d_ws, size_t ws_size,
                              hipStream_t stream) {
    const float* x     = (const float*)d_in[0];
    const float* s     = (const float*)d_in[1];
    const int*   ei    = (const int*)d_in[2];
    const float* gcn_W = (const float*)d_in[3];
    const float* gcn_b = (const float*)d_in[4];
    const float* w1W   = (const float*)d_in[5];
    const float* w1b   = (const float*)d_in[6];
    const float* w2W   = (const float*)d_in[7];
    const float* w2b   = (const float*)d_in[8];
    const float* ga    = (const float*)d_in[9];

    float* h_out = (float*)d_out;                               // N x 128
    float* g_out = (float*)d_out + (size_t)N_NODES * 128;       // N x 64

    size_t off = 0;
    char* wsb = (char*)d_ws;
    auto take = [&](size_t bytes) {
        void* p = wsb + off;
        off = (off + bytes + 255) & ~(size_t)255;
        return p;
    };
    int*    cnt     = (int*)take((size_t)N_NODES * 4);
    int*    ptrb    = (int*)take((size_t)(N_NODES + 1) * 4);
    int*    aux     = (int*)take((size_t)ET * 4);
    float*  dinv    = (float*)take((size_t)N_NODES * 4);
    int*    eidx    = (int*)take((size_t)ET * 4);
    __half* h2      = (__half*)take((size_t)N_NODES * 128 * 2);
    __half* utbuf   = (__half*)take((size_t)N_NODES * 64 * 2);
    float*  basebuf = (float*)take((size_t)N_NODES * 64 * 4);
    float*  ubuf    = (float*)take((size_t)N_NODES * 4);
    int*    bsum    = (int*)take((size_t)NB_SCAN * 4);
    unsigned short* gf_hi = (unsigned short*)take((size_t)8192 * 8 * 2);
    unsigned short* gf_lo = (unsigned short*)take((size_t)8192 * 8 * 2);
    unsigned short* nf_hi = (unsigned short*)take((size_t)4096 * 8 * 2);
    unsigned short* nf_lo = (unsigned short*)take((size_t)4096 * 8 * 2);
    (void)ws_size; (void)in_sizes; (void)n_in; (void)out_size;

    const int* erow = ei;
    const int* ecol = ei + E_EDGES;

    hipMemsetAsync(cnt, 0, (size_t)N_NODES * 4, stream);

    int ge = (ET + 255) / 256;
    count_pos<<<ge, 256, 0, stream>>>(ecol, cnt, aux);
    scan_part1<<<NB_SCAN, 256, 0, stream>>>(cnt, bsum);
    scan_part3<<<NB_SCAN, 256, 0, stream>>>(cnt, bsum, ptrb, dinv);
    bucket<<<ge, 256, 0, stream>>>(erow, ecol, aux, ptrb, eidx);
    prep_w<<<48, 256, 0, stream>>>(gcn_W, w1W, w2W, gf_hi, gf_lo, nf_hi, nf_lo);

    const float* hin = x;
    const float* gin = s;
    for (int l = 0; l < L_LAYERS; ++l) {
        gemm_both<<<2 * MF_BLOCKS, 256, 0, stream>>>(
            hin, gin,
            gf_hi + (size_t)l * 4 * 8 * 64 * 8, gf_lo + (size_t)l * 4 * 8 * 64 * 8,
            nf_hi + (size_t)l * 2 * 8 * 64 * 8, nf_lo + (size_t)l * 2 * 8 * 64 * 8,
            w1b + (size_t)l * 64, w2b + (size_t)l * 64, ga + (size_t)l * 64, dinv,
            h2, basebuf, utbuf, ubuf);
        agg_gcn<<<WAVE_BLOCKS, 256, 0, stream>>>(
            h2, ptrb, eidx, dinv, gcn_b + (size_t)l * 128, h_out,
            (l < L_LAYERS - 1) ? 1 : 0);
        gna_agg<<<WAVE_BLOCKS, 256, 0, stream>>>(
            utbuf, ubuf, ptrb, eidx, basebuf, g_out);
        hin = h_out;
        gin = g_out;
    }
}

// Round 13
// 480.131 us; speedup vs baseline: 1.0313x; 1.0313x over previous
//
#include <hip/hip_runtime.h>
#include <hip/hip_fp16.h>
#include <math.h>

#define N_NODES 50000
#define E_EDGES 800000
#define ET (E_EDGES + N_NODES)   // edges + self loops
#define L_LAYERS 4
#define NB_SCAN ((N_NODES + 255) / 256)   // 196
#define MF2_BLOCKS ((N_NODES + 127) / 128)  // 391 (128 rows per block)
#define AGG_BLOCKS ((N_NODES / 2 * 64 + 255) / 256)  // 6250 (2 dsts per wave)

typedef __attribute__((ext_vector_type(8))) short short8;
typedef __attribute__((ext_vector_type(4))) float f32x4;

// gelu(x) = 0.5x(1+erf(x/sqrt2)); erf via A&S 7.1.26, |err| <= 1.5e-7.
__device__ __forceinline__ float gelu_f(float x) {
    float z = fabsf(x) * 0.70710678118654752f;
    float t = __fdividef(1.0f, fmaf(0.3275911f, z, 1.0f));
    float p = t * fmaf(t, fmaf(t, fmaf(t, fmaf(t, 1.061405429f, -1.453152027f),
                                       1.421413741f), -0.284496736f),
                       0.254829592f);
    float e = __expf(-z * z);
    float erfz = copysignf(fmaf(-p, e, 1.0f), x);
    return 0.5f * x * (1.0f + erfz);
}

__device__ __forceinline__ void split_hl(float x, unsigned short& h, unsigned short& lo) {
    unsigned u = __float_as_uint(x);
    h = (unsigned short)(u >> 16);
    float hif = __uint_as_float(u & 0xffff0000u);
    lo = (unsigned short)(__float_as_uint(x - hif) >> 16);
}

// 8 fp16 (one 16B load) fused convert+scale+accumulate into 8 f32 accs.
// fmaf(fpext(h), m, acc) folds to v_fma_mix_f32 (exact f32 fma).
__device__ __forceinline__ void fma8h(const float4& raw, float m, float* acc) {
    const __half2* h = reinterpret_cast<const __half2*>(&raw);
#pragma unroll
    for (int i = 0; i < 4; ++i) {
        float2 f = __half22float2(h[i]);
        acc[2 * i]     = fmaf(f.x, m, acc[2 * i]);
        acc[2 * i + 1] = fmaf(f.y, m, acc[2 * i + 1]);
    }
}

// ---------------- graph preprocessing ----------------

__global__ __launch_bounds__(256) void count_pos(const int* __restrict__ ecol,
                                                 int* __restrict__ cnt,
                                                 int* __restrict__ aux) {
    int e = blockIdx.x * 256 + threadIdx.x;
    if (e >= ET) return;
    int c = (e < E_EDGES) ? ecol[e] : (e - E_EDGES);
    aux[e] = atomicAdd(&cnt[c], 1);
}

__global__ __launch_bounds__(256) void scan_part1(const int* __restrict__ cnt,
                                                  int* __restrict__ bsum) {
    __shared__ int red[256];
    int t = threadIdx.x;
    int i = blockIdx.x * 256 + t;
    red[t] = (i < N_NODES) ? cnt[i] : 0;
    __syncthreads();
#pragma unroll
    for (int off = 128; off; off >>= 1) {
        if (t < off) red[t] += red[t + off];
        __syncthreads();
    }
    if (t == 0) bsum[blockIdx.x] = red[0];
}

// scan_part3 with scan_part2 folded in: per-block reduce of preceding bsum
// entries (raw block sums; NB_SCAN=196 < 256) gives this block's base.
__global__ __launch_bounds__(256) void scan_part3(const int* __restrict__ cnt,
                                                  const int* __restrict__ bsum,
                                                  int* __restrict__ ptrb,
                                                  float* __restrict__ dinv) {
    __shared__ int red[256];
    __shared__ int sh[256];
    int t = threadIdx.x;
    // base = sum of bsum[j] for j < blockIdx.x
    red[t] = (t < (int)blockIdx.x) ? bsum[t] : 0;
    __syncthreads();
#pragma unroll
    for (int off = 128; off; off >>= 1) {
        if (t < off) red[t] += red[t + off];
        __syncthreads();
    }
    int base = red[0];
    int i = blockIdx.x * 256 + t;
    int v = (i < N_NODES) ? cnt[i] : 0;
    sh[t] = v;
    __syncthreads();
    for (int off = 1; off < 256; off <<= 1) {
        int u = (t >= off) ? sh[t - off] : 0;
        __syncthreads();
        sh[t] += u;
        __syncthreads();
    }
    int excl = sh[t] - v + base;
    if (i < N_NODES) {
        ptrb[i] = excl;
        dinv[i] = rsqrtf((float)v);   // deg >= 1 (self loop)
    }
    if (i == N_NODES - 1) ptrb[N_NODES] = excl + v;
}

// separable norm: only src index needed per edge (dinv folded into tables/out)
__global__ __launch_bounds__(256) void bucket(const int* __restrict__ erow,
                                              const int* __restrict__ ecol,
                                              const int* __restrict__ aux,
                                              const int* __restrict__ ptrb,
                                              int* __restrict__ eidx) {
    int e = blockIdx.x * 256 + threadIdx.x;
    if (e >= ET) return;
    int r, c;
    if (e < E_EDGES) { r = erow[e]; c = ecol[e]; }
    else             { r = e - E_EDGES; c = r; }
    int pos = ptrb[c] + aux[e];
    eidx[pos] = r;
}

// ---------------- W pre-layout: hi/lo bf16 in B-fragment lane order ----------------
// Fragment: B[k = q*8+j][n], lane = q*16+n. Storage [layer][s][nt][lane][j], 16B/lane.
// gcn: s=0..3 (K=128), nt=0..7 (N=128).  gna: s=0..1 (K=64), nt=0..7 (w1 cols|w2 cols).

__global__ __launch_bounds__(256) void prep_w(const float* __restrict__ gcn_W,
                                              const float* __restrict__ w1W,
                                              const float* __restrict__ w2W,
                                              unsigned short* __restrict__ gf_hi,
                                              unsigned short* __restrict__ gf_lo,
                                              unsigned short* __restrict__ nf_hi,
                                              unsigned short* __restrict__ nf_lo) {
    int idx = blockIdx.x * 256 + threadIdx.x;
    if (idx < 8192) {                       // gcn: 4 layer x 4 s x 8 nt x 64 lane
        int lane = idx & 63, nt = (idx >> 6) & 7, s = (idx >> 9) & 3, layer = idx >> 11;
        int q = lane >> 4, n = lane & 15;
        const float* W = gcn_W + (size_t)layer * 128 * 128;
        size_t o = (size_t)idx * 8;
#pragma unroll
        for (int j = 0; j < 8; ++j) {
            float x = W[(size_t)(s * 32 + q * 8 + j) * 128 + nt * 16 + n];
            unsigned short h, lo;
            split_hl(x, h, lo);
            gf_hi[o + j] = h; gf_lo[o + j] = lo;
        }
    } else if (idx < 8192 + 4096) {         // gna: 4 layer x 2 s x 8 nt x 64 lane
        int t = idx - 8192;
        int lane = t & 63, nt = (t >> 6) & 7, s = (t >> 9) & 1, layer = t >> 10;
        int q = lane >> 4, n = lane & 15;
        int col = nt * 16 + n;              // <64 -> w1, >=64 -> w2
        const float* W = (col < 64) ? (w1W + (size_t)layer * 64 * 64)
                                    : (w2W + (size_t)layer * 64 * 64);
        int c = col & 63;
        size_t o = (size_t)t * 8;
#pragma unroll
        for (int j = 0; j < 8; ++j) {
            float x = W[(size_t)(s * 32 + q * 8 + j) * 64 + c];
            unsigned short h, lo;
            split_hl(x, h, lo);
            nf_hi[o + j] = h; nf_lo[o + j] = lo;
        }
    }
}

// ---------------- MFMA GEMM core, 2 row-groups per wave (R9, best-measured) -----

__device__ __forceinline__ void mfma_steps2(const float* __restrict__ A, int Kfull,
                                            int nsteps,
                                            const unsigned short* __restrict__ wfh,
                                            const unsigned short* __restrict__ wfl,
                                            const int* arow, const bool* avalid,
                                            int lq, int l, f32x4 acc[2][8]) {
    for (int s = 0; s < nsteps; ++s) {
        short8 ah[2], al[2];
#pragma unroll
        for (int g = 0; g < 2; ++g) {
            float4 a0 = make_float4(0.f, 0.f, 0.f, 0.f);
            float4 a1 = make_float4(0.f, 0.f, 0.f, 0.f);
            if (avalid[g]) {
                const float* ap = A + (size_t)arow[g] * Kfull + s * 32 + lq * 8;
                a0 = *(const float4*)ap;
                a1 = *(const float4*)(ap + 4);
            }
            float xs[8] = {a0.x, a0.y, a0.z, a0.w, a1.x, a1.y, a1.z, a1.w};
#pragma unroll
            for (int c = 0; c < 8; ++c) {
                unsigned short h, lo;
                split_hl(xs[c], h, lo);
                ah[g][c] = (short)h; al[g][c] = (short)lo;
            }
        }
#pragma unroll
        for (int nt = 0; nt < 8; ++nt) {
            size_t fo = ((size_t)(s * 8 + nt) * 64 + l) * 8;
            short8 wh = *(const short8*)(wfh + fo);
            short8 wl = *(const short8*)(wfl + fo);
#pragma unroll
            for (int g = 0; g < 2; ++g) {
                acc[g][nt] = __builtin_amdgcn_mfma_f32_16x16x32_bf16(ah[g], wh, acc[g][nt], 0, 0, 0);
                acc[g][nt] = __builtin_amdgcn_mfma_f32_16x16x32_bf16(ah[g], wl, acc[g][nt], 0, 0, 0);
                acc[g][nt] = __builtin_amdgcn_mfma_f32_16x16x32_bf16(al[g], wh, acc[g][nt], 0, 0, 0);
            }
        }
    }
}

// Fused per-layer GEMM: blocks [0, MF2_BLOCKS) do GCN h2 = dinv[row]*(A0 @ W)
// (src-side norm pre-folded), stored FP16 (gather table); blocks
// [MF2_BLOCKS, 2*MF2_BLOCKS) do GNA:
//   base = A1@W1+b1 (f32); t = A1@W2+b2; ta = t@avec; u = exp(-ta);
//   ut = u * t stored FP16 (gather table), ub = u (f32, L2-hot).
// (softmax identity: w_e = exp(ta_dst - ta_src)/sum = exp(-ta_src)/sum exp(-ta_src))
// Block covers 128 rows: wave w rows = m0 + w*32 + g*16 + (lane&15), g = 0,1.

__global__ __launch_bounds__(256) void gemm_both(
    const float* __restrict__ A0, const float* __restrict__ A1,
    const unsigned short* __restrict__ gfh, const unsigned short* __restrict__ gfl,
    const unsigned short* __restrict__ nfh, const unsigned short* __restrict__ nfl,
    const float* __restrict__ b1, const float* __restrict__ b2,
    const float* __restrict__ avec, const float* __restrict__ dinv,
    __half* __restrict__ h2, float* __restrict__ baseb,
    __half* __restrict__ ut, float* __restrict__ ub) {
    int tid = threadIdx.x;
    int w  = tid >> 6;
    int l  = tid & 63;
    int lq = l >> 4;
    int ln = l & 15;
    bool isg = blockIdx.x >= MF2_BLOCKS;
    int blk = isg ? (blockIdx.x - MF2_BLOCKS) : blockIdx.x;
    int m0 = blk * 128;
    int arow[2];
    bool avalid[2];
#pragma unroll
    for (int g = 0; g < 2; ++g) {
        arow[g] = m0 + w * 32 + g * 16 + ln;
        avalid[g] = arow[g] < N_NODES;
    }

    f32x4 acc[2][8];
#pragma unroll
    for (int g = 0; g < 2; ++g)
#pragma unroll
        for (int i = 0; i < 8; ++i) acc[g][i] = (f32x4){0.f, 0.f, 0.f, 0.f};

    if (!isg) {
        mfma_steps2(A0, 128, 4, gfh, gfl, arow, avalid, lq, l, acc);
        // C layout: col = ln (per nt tile), row-in-tile = lq*4 + r (verified)
#pragma unroll
        for (int g = 0; g < 2; ++g) {
            float dv[4];
#pragma unroll
            for (int r = 0; r < 4; ++r) {
                int row = m0 + w * 32 + g * 16 + lq * 4 + r;
                dv[r] = (row < N_NODES) ? dinv[row] : 0.f;
            }
#pragma unroll
            for (int nt = 0; nt < 8; ++nt) {
                int col = nt * 16 + ln;
#pragma unroll
                for (int r = 0; r < 4; ++r) {
                    int row = m0 + w * 32 + g * 16 + lq * 4 + r;
                    if (row < N_NODES)
                        h2[(size_t)row * 128 + col] = __float2half(acc[g][nt][r] * dv[r]);
                }
            }
        }
    } else {
        mfma_steps2(A1, 64, 2, nfh, nfl, arow, avalid, lq, l, acc);
#pragma unroll
        for (int g = 0; g < 2; ++g) {
            // base = A1@W1 + b1
#pragma unroll
            for (int nt = 0; nt < 4; ++nt) {
                int col = nt * 16 + ln;
                float bb = b1[col];
#pragma unroll
                for (int r = 0; r < 4; ++r) {
                    int row = m0 + w * 32 + g * 16 + lq * 4 + r;
                    if (row < N_NODES) baseb[(size_t)row * 64 + col] = acc[g][nt][r] + bb;
                }
            }
            // t = A1@W2 + b2; ta = t @ avec (row-reduce over 16 lanes)
            float pa[4] = {0.f, 0.f, 0.f, 0.f};
            float t2s[4][4];
#pragma unroll
            for (int nt = 4; nt < 8; ++nt) {
                int col = (nt - 4) * 16 + ln;
                float bb = b2[col];
                float av = avec[col];
#pragma unroll
                for (int r = 0; r < 4; ++r) {
                    float t2 = acc[g][nt][r] + bb;
                    t2s[nt - 4][r] = t2;
                    pa[r] += t2 * av;
                }
            }
#pragma unroll
            for (int r = 0; r < 4; ++r) {
                pa[r] += __shfl_xor(pa[r], 1);
                pa[r] += __shfl_xor(pa[r], 2);
                pa[r] += __shfl_xor(pa[r], 4);
                pa[r] += __shfl_xor(pa[r], 8);
            }
            float ur[4];
#pragma unroll
            for (int r = 0; r < 4; ++r) ur[r] = expf(-pa[r]);
            // ut = u * t (fp16)  and u per row (f32)
#pragma unroll
            for (int nt = 0; nt < 4; ++nt) {
                int col = nt * 16 + ln;
#pragma unroll
                for (int r = 0; r < 4; ++r) {
                    int row = m0 + w * 32 + g * 16 + lq * 4 + r;
                    if (row < N_NODES)
                        ut[(size_t)row * 64 + col] = __float2half(t2s[nt][r] * ur[r]);
                }
            }
            if (ln == 0) {
#pragma unroll
                for (int r = 0; r < 4; ++r) {
                    int row = m0 + w * 32 + g * 16 + lq * 4 + r;
                    if (row < N_NODES) ub[row] = ur[r];
                }
            }
        }
    }
}

// ---------------- GCN edge aggregation (TWO dsts per wave) ---------------------
// Each 32-lane half serves its own dst: 16 lanes x 16B cover the 256B fp16 row,
// 2 edge slots per half. Wave count halves; prologue/reduce/epilogue amortized
// over 2 dsts. __shfl indices offset by half*32 -> each half reads only its own
// lanes. Distributed epilogue: each lane covers 4 cols (float4 store).

__global__ __launch_bounds__(256) void agg_gcn(const __half* __restrict__ h2,
                                               const int* __restrict__ ptrb,
                                               const int* __restrict__ eidx,
                                               const float* __restrict__ dinv,
                                               const float* __restrict__ bias,
                                               float* __restrict__ out,
                                               int apply_gelu) {
    int widx = (blockIdx.x * 256 + (int)threadIdx.x) >> 6;
    int lane = threadIdx.x & 63;
    int half = lane >> 5;
    int hl   = lane & 31;
    int dst  = widx * 2 + half;
    if (dst >= N_NODES) return;           // N even: both halves valid together
    int sub = hl >> 4;                    // 0..1 : edge slot within half
    int fl  = hl & 15;                    // 16 groups x 8 cols = 128
    int p0 = ptrb[dst], p1 = ptrb[dst + 1];
    float acc[8];
#pragma unroll
    for (int i = 0; i < 8; ++i) acc[i] = 0.f;
    for (int p = p0; p < p1; p += 32) {
        int nb = min(32, p1 - p);            // half-wave uniform
        int srcs = (hl < nb) ? eidx[p + hl] : 0;
        for (int eb = 0; eb < nb; eb += 16) { // uniform within half
            int   sv[8];
            float mk[8];
#pragma unroll
            for (int k = 0; k < 8; ++k) {
                int e = eb + sub + 2 * k;
                int c = half * 32 + min(e, nb - 1);
                sv[k] = __shfl(srcs, c);
                mk[k] = (e < nb) ? 1.f : 0.f;
            }
            float4 raw[8];
#pragma unroll
            for (int k = 0; k < 8; ++k)
                raw[k] = *(const float4*)(h2 + (size_t)sv[k] * 128 + fl * 8);
#pragma unroll
            for (int k = 0; k < 8; ++k) fma8h(raw[k], mk[k], acc);
        }
    }
    // reduce across the 2 subs (xor 16 stays within the half)
#pragma unroll
    for (int i = 0; i < 8; ++i) acc[i] += __shfl_xor(acc[i], 16);
    // distributed epilogue: lane covers cols c0 = fl*8 + 4*sub .. +3
    {
        float dd = dinv[dst];
        int c0 = fl * 8 + 4 * sub;
        float4 bb = *(const float4*)(bias + c0);
        float v0 = fmaf(dd, acc[4 * sub + 0], bb.x);
        float v1 = fmaf(dd, acc[4 * sub + 1], bb.y);
        float v2 = fmaf(dd, acc[4 * sub + 2], bb.z);
        float v3 = fmaf(dd, acc[4 * sub + 3], bb.w);
        if (apply_gelu) {
            v0 = gelu_f(v0); v1 = gelu_f(v1); v2 = gelu_f(v2); v3 = gelu_f(v3);
        }
        *(float4*)(out + (size_t)dst * 128 + c0) = make_float4(v0, v1, v2, v3);
    }
}

// ---------------- GNA edge aggregation (TWO dsts per wave) ---------------------
// Each 32-lane half serves its own dst: 8 lanes x 16B cover the 128B fp16 row,
// 4 edge slots per half. ut rows pre-scaled by u=exp(-ta_src); se sums ub[src].
// Distributed epilogue: each lane covers 2 cols (float2 store).

__global__ __launch_bounds__(256) void gna_agg(const __half* __restrict__ ut,
                                               const float* __restrict__ ub,
                                               const int* __restrict__ ptrb,
                                               const int* __restrict__ eidx,
                                               const float* __restrict__ base,
                                               float* __restrict__ gout) {
    int widx = (blockIdx.x * 256 + (int)threadIdx.x) >> 6;
    int lane = threadIdx.x & 63;
    int half = lane >> 5;
    int hl   = lane & 31;
    int dst  = widx * 2 + half;
    if (dst >= N_NODES) return;
    int sub = hl >> 3;                    // 0..3 : edge slot within half
    int fl  = hl & 7;                     // 8 groups x 8 cols = 64
    int p0 = ptrb[dst], p1 = ptrb[dst + 1];
    float se = 0.f;
    float acc[8];
#pragma unroll
    for (int i = 0; i < 8; ++i) acc[i] = 0.f;
    for (int p = p0; p < p1; p += 32) {
        int nb = min(32, p1 - p);            // half-wave uniform
        int srcs = (hl < nb) ? eidx[p + hl] : 0;
        if (hl < nb) se += ub[srcs];         // L2-hot 200 KB table
        // 32 slots in one pass: e = sub + 4k, k = 0..7
        int   sv[8];
        float mk[8];
#pragma unroll
        for (int k = 0; k < 8; ++k) {
            int e = sub + 4 * k;
            int c = half * 32 + min(e, nb - 1);
            sv[k] = __shfl(srcs, c);
            mk[k] = (e < nb) ? 1.f : 0.f;
        }
        float4 raw[8];
#pragma unroll
        for (int k = 0; k < 8; ++k)
            raw[k] = *(const float4*)(ut + (size_t)sv[k] * 64 + fl * 8);
#pragma unroll
        for (int k = 0; k < 8; ++k) fma8h(raw[k], mk[k], acc);
    }
    // se reduce within half (offsets 1..16)
#pragma unroll
    for (int off = 1; off <= 16; off <<= 1) se += __shfl_xor(se, off);
    // acc reduce across the 4 subs (xor 8,16 stay within the half)
#pragma unroll
    for (int off = 8; off <= 16; off <<= 1)
#pragma unroll
        for (int i = 0; i < 8; ++i) acc[i] += __shfl_xor(acc[i], off);
    // distributed epilogue: lane covers cols c0 = fl*8 + 2*sub .. +1
    {
        float winv = __fdividef(1.0f, se + 1e-16f);
        int c0 = fl * 8 + 2 * sub;
        float2 bs = *(const float2*)(base + (size_t)dst * 64 + c0);
        float v0 = gelu_f(fmaf(acc[2 * sub + 0], winv, bs.x));
        float v1 = gelu_f(fmaf(acc[2 * sub + 1], winv, bs.y));
        *(float2*)(gout + (size_t)dst * 64 + c0) = make_float2(v0, v1);
    }
}

// ---------------- launch ----------------

extern "C" void kernel_launch(void* const* d_in, const int* in_sizes, int n_in,
                              void* d_out, int out_size, void* d_ws, size_t ws_size,
                              hipStream_t stream) {
    const float* x     = (const float*)d_in[0];
    const float* s     = (const float*)d_in[1];
    const int*   ei    = (const int*)d_in[2];
    const float* gcn_W = (const float*)d_in[3];
    const float* gcn_b = (const float*)d_in[4];
    const float* w1W   = (const float*)d_in[5];
    const float* w1b   = (const float*)d_in[6];
    const float* w2W   = (const float*)d_in[7];
    const float* w2b   = (const float*)d_in[8];
    const float* ga    = (const float*)d_in[9];

    float* h_out = (float*)d_out;                               // N x 128
    float* g_out = (float*)d_out + (size_t)N_NODES * 128;       // N x 64

    size_t off = 0;
    char* wsb = (char*)d_ws;
    auto take = [&](size_t bytes) {
        void* p = wsb + off;
        off = (off + bytes + 255) & ~(size_t)255;
        return p;
    };
    int*    cnt     = (int*)take((size_t)N_NODES * 4);
    int*    ptrb    = (int*)take((size_t)(N_NODES + 1) * 4);
    int*    aux     = (int*)take((size_t)ET * 4);
    float*  dinv    = (float*)take((size_t)N_NODES * 4);
    int*    eidx    = (int*)take((size_t)ET * 4);
    __half* h2      = (__half*)take((size_t)N_NODES * 128 * 2);
    __half* utbuf   = (__half*)take((size_t)N_NODES * 64 * 2);
    float*  basebuf = (float*)take((size_t)N_NODES * 64 * 4);
    float*  ubuf    = (float*)take((size_t)N_NODES * 4);
    int*    bsum    = (int*)take((size_t)NB_SCAN * 4);
    unsigned short* gf_hi = (unsigned short*)take((size_t)8192 * 8 * 2);
    unsigned short* gf_lo = (unsigned short*)take((size_t)8192 * 8 * 2);
    unsigned short* nf_hi = (unsigned short*)take((size_t)4096 * 8 * 2);
    unsigned short* nf_lo = (unsigned short*)take((size_t)4096 * 8 * 2);
    (void)ws_size; (void)in_sizes; (void)n_in; (void)out_size;

    const int* erow = ei;
    const int* ecol = ei + E_EDGES;

    hipMemsetAsync(cnt, 0, (size_t)N_NODES * 4, stream);

    int ge = (ET + 255) / 256;
    count_pos<<<ge, 256, 0, stream>>>(ecol, cnt, aux);
    scan_part1<<<NB_SCAN, 256, 0, stream>>>(cnt, bsum);
    scan_part3<<<NB_SCAN, 256, 0, stream>>>(cnt, bsum, ptrb, dinv);
    bucket<<<ge, 256, 0, stream>>>(erow, ecol, aux, ptrb, eidx);
    prep_w<<<48, 256, 0, stream>>>(gcn_W, w1W, w2W, gf_hi, gf_lo, nf_hi, nf_lo);

    const float* hin = x;
    const float* gin = s;
    for (int l = 0; l < L_LAYERS; ++l) {
        gemm_both<<<2 * MF2_BLOCKS, 256, 0, stream>>>(
            hin, gin,
            gf_hi + (size_t)l * 4 * 8 * 64 * 8, gf_lo + (size_t)l * 4 * 8 * 64 * 8,
            nf_hi + (size_t)l * 2 * 8 * 64 * 8, nf_lo + (size_t)l * 2 * 8 * 64 * 8,
            w1b + (size_t)l * 64, w2b + (size_t)l * 64, ga + (size_t)l * 64, dinv,
            h2, basebuf, utbuf, ubuf);
        agg_gcn<<<AGG_BLOCKS, 256, 0, stream>>>(
            h2, ptrb, eidx, dinv, gcn_b + (size_t)l * 128, h_out,
            (l < L_LAYERS - 1) ? 1 : 0);
        gna_agg<<<AGG_BLOCKS, 256, 0, stream>>>(
            utbuf, ubuf, ptrb, eidx, basebuf, g_out);
        hin = h_out;
        gin = g_out;
    }
}

// Round 14
// 470.464 us; speedup vs baseline: 1.0525x; 1.0205x over previous
//
#include <hip/hip_runtime.h>
#include <hip/hip_fp16.h>
#include <math.h>

#define N_NODES 50000
#define E_EDGES 800000
#define ET (E_EDGES + N_NODES)   // edges + self loops
#define L_LAYERS 4
#define NB_SCAN ((N_NODES + 255) / 256)   // 196
#define MF2_BLOCKS ((N_NODES + 127) / 128)  // 391 (128 rows per block)
#define AGG_BLOCKS ((N_NODES / 2 * 64 + 255) / 256)  // 6250 (2 dsts per wave)

typedef __attribute__((ext_vector_type(8))) short short8;
typedef __attribute__((ext_vector_type(4))) float f32x4;

// gelu(x) = 0.5x(1+erf(x/sqrt2)); erf via A&S 7.1.26, |err| <= 1.5e-7.
__device__ __forceinline__ float gelu_f(float x) {
    float z = fabsf(x) * 0.70710678118654752f;
    float t = __fdividef(1.0f, fmaf(0.3275911f, z, 1.0f));
    float p = t * fmaf(t, fmaf(t, fmaf(t, fmaf(t, 1.061405429f, -1.453152027f),
                                       1.421413741f), -0.284496736f),
                       0.254829592f);
    float e = __expf(-z * z);
    float erfz = copysignf(fmaf(-p, e, 1.0f), x);
    return 0.5f * x * (1.0f + erfz);
}

__device__ __forceinline__ void split_hl(float x, unsigned short& h, unsigned short& lo) {
    unsigned u = __float_as_uint(x);
    h = (unsigned short)(u >> 16);
    float hif = __uint_as_float(u & 0xffff0000u);
    lo = (unsigned short)(__float_as_uint(x - hif) >> 16);
}

// 8 fp16 (one 16B load) fused convert+scale+accumulate into 8 f32 accs.
// fmaf(fpext(h), m, acc) folds to v_fma_mix_f32 (exact f32 fma).
__device__ __forceinline__ void fma8h(const float4& raw, float m, float* acc) {
    const __half2* h = reinterpret_cast<const __half2*>(&raw);
#pragma unroll
    for (int i = 0; i < 4; ++i) {
        float2 f = __half22float2(h[i]);
        acc[2 * i]     = fmaf(f.x, m, acc[2 * i]);
        acc[2 * i + 1] = fmaf(f.y, m, acc[2 * i + 1]);
    }
}

// ---------------- graph preprocessing ----------------

__global__ __launch_bounds__(256) void count_pos(const int* __restrict__ ecol,
                                                 int* __restrict__ cnt,
                                                 int* __restrict__ aux) {
    int e = blockIdx.x * 256 + threadIdx.x;
    if (e >= ET) return;
    int c = (e < E_EDGES) ? ecol[e] : (e - E_EDGES);
    aux[e] = atomicAdd(&cnt[c], 1);
}

__global__ __launch_bounds__(256) void scan_part1(const int* __restrict__ cnt,
                                                  int* __restrict__ bsum) {
    __shared__ int red[256];
    int t = threadIdx.x;
    int i = blockIdx.x * 256 + t;
    red[t] = (i < N_NODES) ? cnt[i] : 0;
    __syncthreads();
#pragma unroll
    for (int off = 128; off; off >>= 1) {
        if (t < off) red[t] += red[t + off];
        __syncthreads();
    }
    if (t == 0) bsum[blockIdx.x] = red[0];
}

// scan_part3 with scan_part2 folded in: per-block reduce of preceding bsum
// entries (raw block sums; NB_SCAN=196 < 256) gives this block's base.
__global__ __launch_bounds__(256) void scan_part3(const int* __restrict__ cnt,
                                                  const int* __restrict__ bsum,
                                                  int* __restrict__ ptrb,
                                                  float* __restrict__ dinv) {
    __shared__ int red[256];
    __shared__ int sh[256];
    int t = threadIdx.x;
    // base = sum of bsum[j] for j < blockIdx.x
    red[t] = (t < (int)blockIdx.x) ? bsum[t] : 0;
    __syncthreads();
#pragma unroll
    for (int off = 128; off; off >>= 1) {
        if (t < off) red[t] += red[t + off];
        __syncthreads();
    }
    int base = red[0];
    int i = blockIdx.x * 256 + t;
    int v = (i < N_NODES) ? cnt[i] : 0;
    sh[t] = v;
    __syncthreads();
    for (int off = 1; off < 256; off <<= 1) {
        int u = (t >= off) ? sh[t - off] : 0;
        __syncthreads();
        sh[t] += u;
        __syncthreads();
    }
    int excl = sh[t] - v + base;
    if (i < N_NODES) {
        ptrb[i] = excl;
        dinv[i] = rsqrtf((float)v);   // deg >= 1 (self loop)
    }
    if (i == N_NODES - 1) ptrb[N_NODES] = excl + v;
}

// separable norm: only src index needed per edge (dinv folded into tables/out)
__global__ __launch_bounds__(256) void bucket(const int* __restrict__ erow,
                                              const int* __restrict__ ecol,
                                              const int* __restrict__ aux,
                                              const int* __restrict__ ptrb,
                                              int* __restrict__ eidx) {
    int e = blockIdx.x * 256 + threadIdx.x;
    if (e >= ET) return;
    int r, c;
    if (e < E_EDGES) { r = erow[e]; c = ecol[e]; }
    else             { r = e - E_EDGES; c = r; }
    int pos = ptrb[c] + aux[e];
    eidx[pos] = r;
}

// ---------------- W pre-layout: hi/lo bf16 in B-fragment lane order ----------------
// Fragment: B[k = q*8+j][n], lane = q*16+n. Storage [layer][s][nt][lane][j], 16B/lane.
// gcn: s=0..3 (K=128), nt=0..7 (N=128).  gna: s=0..1 (K=64), nt=0..7 (w1 cols|w2 cols).

__global__ __launch_bounds__(256) void prep_w(const float* __restrict__ gcn_W,
                                              const float* __restrict__ w1W,
                                              const float* __restrict__ w2W,
                                              unsigned short* __restrict__ gf_hi,
                                              unsigned short* __restrict__ gf_lo,
                                              unsigned short* __restrict__ nf_hi,
                                              unsigned short* __restrict__ nf_lo) {
    int idx = blockIdx.x * 256 + threadIdx.x;
    if (idx < 8192) {                       // gcn: 4 layer x 4 s x 8 nt x 64 lane
        int lane = idx & 63, nt = (idx >> 6) & 7, s = (idx >> 9) & 3, layer = idx >> 11;
        int q = lane >> 4, n = lane & 15;
        const float* W = gcn_W + (size_t)layer * 128 * 128;
        size_t o = (size_t)idx * 8;
#pragma unroll
        for (int j = 0; j < 8; ++j) {
            float x = W[(size_t)(s * 32 + q * 8 + j) * 128 + nt * 16 + n];
            unsigned short h, lo;
            split_hl(x, h, lo);
            gf_hi[o + j] = h; gf_lo[o + j] = lo;
        }
    } else if (idx < 8192 + 4096) {         // gna: 4 layer x 2 s x 8 nt x 64 lane
        int t = idx - 8192;
        int lane = t & 63, nt = (t >> 6) & 7, s = (t >> 9) & 1, layer = t >> 10;
        int q = lane >> 4, n = lane & 15;
        int col = nt * 16 + n;              // <64 -> w1, >=64 -> w2
        const float* W = (col < 64) ? (w1W + (size_t)layer * 64 * 64)
                                    : (w2W + (size_t)layer * 64 * 64);
        int c = col & 63;
        size_t o = (size_t)t * 8;
#pragma unroll
        for (int j = 0; j < 8; ++j) {
            float x = W[(size_t)(s * 32 + q * 8 + j) * 64 + c];
            unsigned short h, lo;
            split_hl(x, h, lo);
            nf_hi[o + j] = h; nf_lo[o + j] = lo;
        }
    }
}

// ---------------- MFMA GEMM core, 2 row-groups per wave (R9/R13, best-measured) --

__device__ __forceinline__ void mfma_steps2(const float* __restrict__ A, int Kfull,
                                            int nsteps,
                                            const unsigned short* __restrict__ wfh,
                                            const unsigned short* __restrict__ wfl,
                                            const int* arow, const bool* avalid,
                                            int lq, int l, f32x4 acc[2][8]) {
    for (int s = 0; s < nsteps; ++s) {
        short8 ah[2], al[2];
#pragma unroll
        for (int g = 0; g < 2; ++g) {
            float4 a0 = make_float4(0.f, 0.f, 0.f, 0.f);
            float4 a1 = make_float4(0.f, 0.f, 0.f, 0.f);
            if (avalid[g]) {
                const float* ap = A + (size_t)arow[g] * Kfull + s * 32 + lq * 8;
                a0 = *(const float4*)ap;
                a1 = *(const float4*)(ap + 4);
            }
            float xs[8] = {a0.x, a0.y, a0.z, a0.w, a1.x, a1.y, a1.z, a1.w};
#pragma unroll
            for (int c = 0; c < 8; ++c) {
                unsigned short h, lo;
                split_hl(xs[c], h, lo);
                ah[g][c] = (short)h; al[g][c] = (short)lo;
            }
        }
#pragma unroll
        for (int nt = 0; nt < 8; ++nt) {
            size_t fo = ((size_t)(s * 8 + nt) * 64 + l) * 8;
            short8 wh = *(const short8*)(wfh + fo);
            short8 wl = *(const short8*)(wfl + fo);
#pragma unroll
            for (int g = 0; g < 2; ++g) {
                acc[g][nt] = __builtin_amdgcn_mfma_f32_16x16x32_bf16(ah[g], wh, acc[g][nt], 0, 0, 0);
                acc[g][nt] = __builtin_amdgcn_mfma_f32_16x16x32_bf16(ah[g], wl, acc[g][nt], 0, 0, 0);
                acc[g][nt] = __builtin_amdgcn_mfma_f32_16x16x32_bf16(al[g], wh, acc[g][nt], 0, 0, 0);
            }
        }
    }
}

// Fused per-layer GEMM (block = 128 rows, wave w rows m0+w*32+g*16+ln, g=0,1).
// NEW in R14: C-writes go through a 48 KB LDS tile in output layout, then flush
// with coalesced 16B stores. The old epilogue issued 2-byte scalar global
// stores (32/lane) -> 32B sub-sector write transactions; R8 profile showed the
// GEMM moving 52 MB at only 1.2 TB/s effective — write-transaction-bound.

__global__ __launch_bounds__(256) void gemm_both(
    const float* __restrict__ A0, const float* __restrict__ A1,
    const unsigned short* __restrict__ gfh, const unsigned short* __restrict__ gfl,
    const unsigned short* __restrict__ nfh, const unsigned short* __restrict__ nfl,
    const float* __restrict__ b1, const float* __restrict__ b2,
    const float* __restrict__ avec, const float* __restrict__ dinv,
    __half* __restrict__ h2, float* __restrict__ baseb,
    __half* __restrict__ ut, float* __restrict__ ub) {
    __shared__ __align__(16) char smem[49152];   // GCN: 32 KB fp16 C; GNA: 32K f32 base + 16K fp16 ut
    int tid = threadIdx.x;
    int w  = tid >> 6;
    int l  = tid & 63;
    int lq = l >> 4;
    int ln = l & 15;
    bool isg = blockIdx.x >= MF2_BLOCKS;
    int blk = isg ? (blockIdx.x - MF2_BLOCKS) : blockIdx.x;
    int m0 = blk * 128;
    int arow[2];
    bool avalid[2];
#pragma unroll
    for (int g = 0; g < 2; ++g) {
        arow[g] = m0 + w * 32 + g * 16 + ln;
        avalid[g] = arow[g] < N_NODES;
    }

    f32x4 acc[2][8];
#pragma unroll
    for (int g = 0; g < 2; ++g)
#pragma unroll
        for (int i = 0; i < 8; ++i) acc[g][i] = (f32x4){0.f, 0.f, 0.f, 0.f};

    if (!isg) {
        mfma_steps2(A0, 128, 4, gfh, gfl, arow, avalid, lq, l, acc);
        // stage C into LDS in output layout [128][128] fp16
        __half* ldc = (__half*)smem;
#pragma unroll
        for (int g = 0; g < 2; ++g) {
            float dv[4];
#pragma unroll
            for (int r = 0; r < 4; ++r) {
                int row = m0 + w * 32 + g * 16 + lq * 4 + r;
                dv[r] = (row < N_NODES) ? dinv[row] : 0.f;
            }
#pragma unroll
            for (int nt = 0; nt < 8; ++nt) {
                int col = nt * 16 + ln;
#pragma unroll
                for (int r = 0; r < 4; ++r) {
                    int lr = w * 32 + g * 16 + lq * 4 + r;
                    ldc[lr * 128 + col] = __float2half(acc[g][nt][r] * dv[r]);
                }
            }
        }
        __syncthreads();
        // flush: thread t -> row = t>>1, 128B segment = t&1 (8 x uint4)
        {
            int row = tid >> 1, seg = tid & 1;
            int grow = m0 + row;
            if (grow < N_NODES) {
                const uint4* src = (const uint4*)(ldc + row * 128 + seg * 64);
                uint4* dst = (uint4*)(h2 + (size_t)grow * 128 + seg * 64);
#pragma unroll
                for (int i = 0; i < 8; ++i) dst[i] = src[i];
            }
        }
    } else {
        mfma_steps2(A1, 64, 2, nfh, nfl, arow, avalid, lq, l, acc);
        float* ldf = (float*)smem;                      // base [128][64] f32
        __half* ldh = (__half*)(smem + 32768);          // ut   [128][64] fp16
#pragma unroll
        for (int g = 0; g < 2; ++g) {
            // base = A1@W1 + b1 -> LDS
#pragma unroll
            for (int nt = 0; nt < 4; ++nt) {
                int col = nt * 16 + ln;
                float bb = b1[col];
#pragma unroll
                for (int r = 0; r < 4; ++r) {
                    int lr = w * 32 + g * 16 + lq * 4 + r;
                    ldf[lr * 64 + col] = acc[g][nt][r] + bb;
                }
            }
            // t = A1@W2 + b2; ta = t @ avec (row-reduce over 16 lanes)
            float pa[4] = {0.f, 0.f, 0.f, 0.f};
            float t2s[4][4];
#pragma unroll
            for (int nt = 4; nt < 8; ++nt) {
                int col = (nt - 4) * 16 + ln;
                float bb = b2[col];
                float av = avec[col];
#pragma unroll
                for (int r = 0; r < 4; ++r) {
                    float t2 = acc[g][nt][r] + bb;
                    t2s[nt - 4][r] = t2;
                    pa[r] += t2 * av;
                }
            }
#pragma unroll
            for (int r = 0; r < 4; ++r) {
                pa[r] += __shfl_xor(pa[r], 1);
                pa[r] += __shfl_xor(pa[r], 2);
                pa[r] += __shfl_xor(pa[r], 4);
                pa[r] += __shfl_xor(pa[r], 8);
            }
            float ur[4];
#pragma unroll
            for (int r = 0; r < 4; ++r) ur[r] = expf(-pa[r]);
            // ut = u * t (fp16) -> LDS
#pragma unroll
            for (int nt = 0; nt < 4; ++nt) {
                int col = nt * 16 + ln;
#pragma unroll
                for (int r = 0; r < 4; ++r) {
                    int lr = w * 32 + g * 16 + lq * 4 + r;
                    ldh[lr * 64 + col] = __float2half(t2s[nt][r] * ur[r]);
                }
            }
            if (ln == 0) {
#pragma unroll
                for (int r = 0; r < 4; ++r) {
                    int row = m0 + w * 32 + g * 16 + lq * 4 + r;
                    if (row < N_NODES) ub[row] = ur[r];
                }
            }
        }
        __syncthreads();
        // flush base (256B/row: thread t -> row = t>>1, 128B seg = t&1)
        {
            int row = tid >> 1, seg = tid & 1;
            int grow = m0 + row;
            if (grow < N_NODES) {
                const uint4* src = (const uint4*)(ldf + row * 64 + seg * 32);
                uint4* dst = (uint4*)(baseb + (size_t)grow * 64 + seg * 32);
#pragma unroll
                for (int i = 0; i < 8; ++i) dst[i] = src[i];
                // flush ut (128B/row: 64B seg = 4 x uint4)
                const uint4* srh = (const uint4*)(ldh + row * 64 + seg * 32);
                uint4* dsh = (uint4*)(ut + (size_t)grow * 64 + seg * 32);
#pragma unroll
                for (int i = 0; i < 4; ++i) dsh[i] = srh[i];
            }
        }
    }
}

// ---------------- GCN edge aggregation (TWO dsts per wave) ---------------------
// Each 32-lane half serves its own dst: 16 lanes x 16B cover the 256B fp16 row,
// 2 edge slots per half. Distributed epilogue: each lane covers 4 cols.

__global__ __launch_bounds__(256) void agg_gcn(const __half* __restrict__ h2,
                                               const int* __restrict__ ptrb,
                                               const int* __restrict__ eidx,
                                               const float* __restrict__ dinv,
                                               const float* __restrict__ bias,
                                               float* __restrict__ out,
                                               int apply_gelu) {
    int widx = (blockIdx.x * 256 + (int)threadIdx.x) >> 6;
    int lane = threadIdx.x & 63;
    int half = lane >> 5;
    int hl   = lane & 31;
    int dst  = widx * 2 + half;
    if (dst >= N_NODES) return;           // N even: both halves valid together
    int sub = hl >> 4;                    // 0..1 : edge slot within half
    int fl  = hl & 15;                    // 16 groups x 8 cols = 128
    int p0 = ptrb[dst], p1 = ptrb[dst + 1];
    float acc[8];
#pragma unroll
    for (int i = 0; i < 8; ++i) acc[i] = 0.f;
    for (int p = p0; p < p1; p += 32) {
        int nb = min(32, p1 - p);            // half-wave uniform
        int srcs = (hl < nb) ? eidx[p + hl] : 0;
        for (int eb = 0; eb < nb; eb += 16) { // uniform within half
            int   sv[8];
            float mk[8];
#pragma unroll
            for (int k = 0; k < 8; ++k) {
                int e = eb + sub + 2 * k;
                int c = half * 32 + min(e, nb - 1);
                sv[k] = __shfl(srcs, c);
                mk[k] = (e < nb) ? 1.f : 0.f;
            }
            float4 raw[8];
#pragma unroll
            for (int k = 0; k < 8; ++k)
                raw[k] = *(const float4*)(h2 + (size_t)sv[k] * 128 + fl * 8);
#pragma unroll
            for (int k = 0; k < 8; ++k) fma8h(raw[k], mk[k], acc);
        }
    }
    // reduce across the 2 subs (xor 16 stays within the half)
#pragma unroll
    for (int i = 0; i < 8; ++i) acc[i] += __shfl_xor(acc[i], 16);
    // distributed epilogue: lane covers cols c0 = fl*8 + 4*sub .. +3
    {
        float dd = dinv[dst];
        int c0 = fl * 8 + 4 * sub;
        float4 bb = *(const float4*)(bias + c0);
        float v0 = fmaf(dd, acc[4 * sub + 0], bb.x);
        float v1 = fmaf(dd, acc[4 * sub + 1], bb.y);
        float v2 = fmaf(dd, acc[4 * sub + 2], bb.z);
        float v3 = fmaf(dd, acc[4 * sub + 3], bb.w);
        if (apply_gelu) {
            v0 = gelu_f(v0); v1 = gelu_f(v1); v2 = gelu_f(v2); v3 = gelu_f(v3);
        }
        *(float4*)(out + (size_t)dst * 128 + c0) = make_float4(v0, v1, v2, v3);
    }
}

// ---------------- GNA edge aggregation (TWO dsts per wave) ---------------------
// Each 32-lane half serves its own dst: 8 lanes x 16B cover the 128B fp16 row,
// 4 edge slots per half. Distributed epilogue: each lane covers 2 cols.

__global__ __launch_bounds__(256) void gna_agg(const __half* __restrict__ ut,
                                               const float* __restrict__ ub,
                                               const int* __restrict__ ptrb,
                                               const int* __restrict__ eidx,
                                               const float* __restrict__ base,
                                               float* __restrict__ gout) {
    int widx = (blockIdx.x * 256 + (int)threadIdx.x) >> 6;
    int lane = threadIdx.x & 63;
    int half = lane >> 5;
    int hl   = lane & 31;
    int dst  = widx * 2 + half;
    if (dst >= N_NODES) return;
    int sub = hl >> 3;                    // 0..3 : edge slot within half
    int fl  = hl & 7;                     // 8 groups x 8 cols = 64
    int p0 = ptrb[dst], p1 = ptrb[dst + 1];
    float se = 0.f;
    float acc[8];
#pragma unroll
    for (int i = 0; i < 8; ++i) acc[i] = 0.f;
    for (int p = p0; p < p1; p += 32) {
        int nb = min(32, p1 - p);            // half-wave uniform
        int srcs = (hl < nb) ? eidx[p + hl] : 0;
        if (hl < nb) se += ub[srcs];         // L2-hot 200 KB table
        // 32 slots in one pass: e = sub + 4k, k = 0..7
        int   sv[8];
        float mk[8];
#pragma unroll
        for (int k = 0; k < 8; ++k) {
            int e = sub + 4 * k;
            int c = half * 32 + min(e, nb - 1);
            sv[k] = __shfl(srcs, c);
            mk[k] = (e < nb) ? 1.f : 0.f;
        }
        float4 raw[8];
#pragma unroll
        for (int k = 0; k < 8; ++k)
            raw[k] = *(const float4*)(ut + (size_t)sv[k] * 64 + fl * 8);
#pragma unroll
        for (int k = 0; k < 8; ++k) fma8h(raw[k], mk[k], acc);
    }
    // se reduce within half (offsets 1..16)
#pragma unroll
    for (int off = 1; off <= 16; off <<= 1) se += __shfl_xor(se, off);
    // acc reduce across the 4 subs (xor 8,16 stay within the half)
#pragma unroll
    for (int off = 8; off <= 16; off <<= 1)
#pragma unroll
        for (int i = 0; i < 8; ++i) acc[i] += __shfl_xor(acc[i], off);
    // distributed epilogue: lane covers cols c0 = fl*8 + 2*sub .. +1
    {
        float winv = __fdividef(1.0f, se + 1e-16f);
        int c0 = fl * 8 + 2 * sub;
        float2 bs = *(const float2*)(base + (size_t)dst * 64 + c0);
        float v0 = gelu_f(fmaf(acc[2 * sub + 0], winv, bs.x));
        float v1 = gelu_f(fmaf(acc[2 * sub + 1], winv, bs.y));
        *(float2*)(gout + (size_t)dst * 64 + c0) = make_float2(v0, v1);
    }
}

// ---------------- launch ----------------

extern "C" void kernel_launch(void* const* d_in, const int* in_sizes, int n_in,
                              void* d_out, int out_size, void* d_ws, size_t ws_size,
                              hipStream_t stream) {
    const float* x     = (const float*)d_in[0];
    const float* s     = (const float*)d_in[1];
    const int*   ei    = (const int*)d_in[2];
    const float* gcn_W = (const float*)d_in[3];
    const float* gcn_b = (const float*)d_in[4];
    const float* w1W   = (const float*)d_in[5];
    const float* w1b   = (const float*)d_in[6];
    const float* w2W   = (const float*)d_in[7];
    const float* w2b   = (const float*)d_in[8];
    const float* ga    = (const float*)d_in[9];

    float* h_out = (float*)d_out;                               // N x 128
    float* g_out = (float*)d_out + (size_t)N_NODES * 128;       // N x 64

    size_t off = 0;
    char* wsb = (char*)d_ws;
    auto take = [&](size_t bytes) {
        void* p = wsb + off;
        off = (off + bytes + 255) & ~(size_t)255;
        return p;
    };
    int*    cnt     = (int*)take((size_t)N_NODES * 4);
    int*    ptrb    = (int*)take((size_t)(N_NODES + 1) * 4);
    int*    aux     = (int*)take((size_t)ET * 4);
    float*  dinv    = (float*)take((size_t)N_NODES * 4);
    int*    eidx    = (int*)take((size_t)ET * 4);
    __half* h2      = (__half*)take((size_t)N_NODES * 128 * 2);
    __half* utbuf   = (__half*)take((size_t)N_NODES * 64 * 2);
    float*  basebuf = (float*)take((size_t)N_NODES * 64 * 4);
    float*  ubuf    = (float*)take((size_t)N_NODES * 4);
    int*    bsum    = (int*)take((size_t)NB_SCAN * 4);
    unsigned short* gf_hi = (unsigned short*)take((size_t)8192 * 8 * 2);
    unsigned short* gf_lo = (unsigned short*)take((size_t)8192 * 8 * 2);
    unsigned short* nf_hi = (unsigned short*)take((size_t)4096 * 8 * 2);
    unsigned short* nf_lo = (unsigned short*)take((size_t)4096 * 8 * 2);
    (void)ws_size; (void)in_sizes; (void)n_in; (void)out_size;

    const int* erow = ei;
    const int* ecol = ei + E_EDGES;

    hipMemsetAsync(cnt, 0, (size_t)N_NODES * 4, stream);

    int ge = (ET + 255) / 256;
    count_pos<<<ge, 256, 0, stream>>>(ecol, cnt, aux);
    scan_part1<<<NB_SCAN, 256, 0, stream>>>(cnt, bsum);
    scan_part3<<<NB_SCAN, 256, 0, stream>>>(cnt, bsum, ptrb, dinv);
    bucket<<<ge, 256, 0, stream>>>(erow, ecol, aux, ptrb, eidx);
    prep_w<<<48, 256, 0, stream>>>(gcn_W, w1W, w2W, gf_hi, gf_lo, nf_hi, nf_lo);

    const float* hin = x;
    const float* gin = s;
    for (int l = 0; l < L_LAYERS; ++l) {
        gemm_both<<<2 * MF2_BLOCKS, 256, 0, stream>>>(
            hin, gin,
            gf_hi + (size_t)l * 4 * 8 * 64 * 8, gf_lo + (size_t)l * 4 * 8 * 64 * 8,
            nf_hi + (size_t)l * 2 * 8 * 64 * 8, nf_lo + (size_t)l * 2 * 8 * 64 * 8,
            w1b + (size_t)l * 64, w2b + (size_t)l * 64, ga + (size_t)l * 64, dinv,
            h2, basebuf, utbuf, ubuf);
        agg_gcn<<<AGG_BLOCKS, 256, 0, stream>>>(
            h2, ptrb, eidx, dinv, gcn_b + (size_t)l * 128, h_out,
            (l < L_LAYERS - 1) ? 1 : 0);
        gna_agg<<<AGG_BLOCKS, 256, 0, stream>>>(
            utbuf, ubuf, ptrb, eidx, basebuf, g_out);
        hin = h_out;
        gin = g_out;
    }
}

// Round 16
// 469.856 us; speedup vs baseline: 1.0538x; 1.0013x over previous
//
#include <hip/hip_runtime.h>
#include <hip/hip_fp16.h>
#include <math.h>

#define N_NODES 50000
#define E_EDGES 800000
#define ET (E_EDGES + N_NODES)   // edges + self loops
#define L_LAYERS 4
#define NB_SCAN ((N_NODES + 255) / 256)   // 196
#define MF_BLOCKS ((N_NODES + 63) / 64)   // 782 (64 rows per block)
#define AGG_BLOCKS ((N_NODES / 2 * 64 + 255) / 256)  // 6250 (2 dsts per wave)

typedef __attribute__((ext_vector_type(8))) short short8;
typedef __attribute__((ext_vector_type(4))) float f32x4;

// gelu(x) = 0.5x(1+erf(x/sqrt2)); erf via A&S 7.1.26, |err| <= 1.5e-7.
__device__ __forceinline__ float gelu_f(float x) {
    float z = fabsf(x) * 0.70710678118654752f;
    float t = __fdividef(1.0f, fmaf(0.3275911f, z, 1.0f));
    float p = t * fmaf(t, fmaf(t, fmaf(t, fmaf(t, 1.061405429f, -1.453152027f),
                                       1.421413741f), -0.284496736f),
                       0.254829592f);
    float e = __expf(-z * z);
    float erfz = copysignf(fmaf(-p, e, 1.0f), x);
    return 0.5f * x * (1.0f + erfz);
}

__device__ __forceinline__ void split_hl(float x, unsigned short& h, unsigned short& lo) {
    unsigned u = __float_as_uint(x);
    h = (unsigned short)(u >> 16);
    float hif = __uint_as_float(u & 0xffff0000u);
    lo = (unsigned short)(__float_as_uint(x - hif) >> 16);
}

// 8 fp16 (one 16B load) fused convert+scale+accumulate into 8 f32 accs.
// fmaf(fpext(h), m, acc) folds to v_fma_mix_f32 (exact f32 fma).
__device__ __forceinline__ void fma8h(const float4& raw, float m, float* acc) {
    const __half2* h = reinterpret_cast<const __half2*>(&raw);
#pragma unroll
    for (int i = 0; i < 4; ++i) {
        float2 f = __half22float2(h[i]);
        acc[2 * i]     = fmaf(f.x, m, acc[2 * i]);
        acc[2 * i + 1] = fmaf(f.y, m, acc[2 * i + 1]);
    }
}

// ---------------- graph preprocessing ----------------

__global__ __launch_bounds__(256) void count_pos(const int* __restrict__ ecol,
                                                 int* __restrict__ cnt,
                                                 int* __restrict__ aux) {
    int e = blockIdx.x * 256 + threadIdx.x;
    if (e >= ET) return;
    int c = (e < E_EDGES) ? ecol[e] : (e - E_EDGES);
    aux[e] = atomicAdd(&cnt[c], 1);
}

__global__ __launch_bounds__(256) void scan_part1(const int* __restrict__ cnt,
                                                  int* __restrict__ bsum) {
    __shared__ int red[256];
    int t = threadIdx.x;
    int i = blockIdx.x * 256 + t;
    red[t] = (i < N_NODES) ? cnt[i] : 0;
    __syncthreads();
#pragma unroll
    for (int off = 128; off; off >>= 1) {
        if (t < off) red[t] += red[t + off];
        __syncthreads();
    }
    if (t == 0) bsum[blockIdx.x] = red[0];
}

// scan_part3 with scan_part2 folded in: per-block reduce of preceding bsum
// entries (raw block sums; NB_SCAN=196 < 256) gives this block's base.
__global__ __launch_bounds__(256) void scan_part3(const int* __restrict__ cnt,
                                                  const int* __restrict__ bsum,
                                                  int* __restrict__ ptrb,
                                                  float* __restrict__ dinv) {
    __shared__ int red[256];
    __shared__ int sh[256];
    int t = threadIdx.x;
    // base = sum of bsum[j] for j < blockIdx.x
    red[t] = (t < (int)blockIdx.x) ? bsum[t] : 0;
    __syncthreads();
#pragma unroll
    for (int off = 128; off; off >>= 1) {
        if (t < off) red[t] += red[t + off];
        __syncthreads();
    }
    int base = red[0];
    int i = blockIdx.x * 256 + t;
    int v = (i < N_NODES) ? cnt[i] : 0;
    sh[t] = v;
    __syncthreads();
    for (int off = 1; off < 256; off <<= 1) {
        int u = (t >= off) ? sh[t - off] : 0;
        __syncthreads();
        sh[t] += u;
        __syncthreads();
    }
    int excl = sh[t] - v + base;
    if (i < N_NODES) {
        ptrb[i] = excl;
        dinv[i] = rsqrtf((float)v);   // deg >= 1 (self loop)
    }
    if (i == N_NODES - 1) ptrb[N_NODES] = excl + v;
}

// separable norm: only src index needed per edge (dinv folded into tables/out)
__global__ __launch_bounds__(256) void bucket(const int* __restrict__ erow,
                                              const int* __restrict__ ecol,
                                              const int* __restrict__ aux,
                                              const int* __restrict__ ptrb,
                                              int* __restrict__ eidx) {
    int e = blockIdx.x * 256 + threadIdx.x;
    if (e >= ET) return;
    int r, c;
    if (e < E_EDGES) { r = erow[e]; c = ecol[e]; }
    else             { r = e - E_EDGES; c = r; }
    int pos = ptrb[c] + aux[e];
    eidx[pos] = r;
}

// ---------------- W pre-layout: hi/lo bf16 in B-fragment lane order ----------------
// Fragment: B[k = q*8+j][n], lane = q*16+n. Storage [layer][s][nt][lane][j], 16B/lane.
// gcn: s=0..3 (K=128), nt=0..7 (N=128).  gna: s=0..1 (K=64), nt=0..7 (w1 cols|w2 cols).

__global__ __launch_bounds__(256) void prep_w(const float* __restrict__ gcn_W,
                                              const float* __restrict__ w1W,
                                              const float* __restrict__ w2W,
                                              unsigned short* __restrict__ gf_hi,
                                              unsigned short* __restrict__ gf_lo,
                                              unsigned short* __restrict__ nf_hi,
                                              unsigned short* __restrict__ nf_lo) {
    int idx = blockIdx.x * 256 + threadIdx.x;
    if (idx < 8192) {                       // gcn: 4 layer x 4 s x 8 nt x 64 lane
        int lane = idx & 63, nt = (idx >> 6) & 7, s = (idx >> 9) & 3, layer = idx >> 11;
        int q = lane >> 4, n = lane & 15;
        const float* W = gcn_W + (size_t)layer * 128 * 128;
        size_t o = (size_t)idx * 8;
#pragma unroll
        for (int j = 0; j < 8; ++j) {
            float x = W[(size_t)(s * 32 + q * 8 + j) * 128 + nt * 16 + n];
            unsigned short h, lo;
            split_hl(x, h, lo);
            gf_hi[o + j] = h; gf_lo[o + j] = lo;
        }
    } else if (idx < 8192 + 4096) {         // gna: 4 layer x 2 s x 8 nt x 64 lane
        int t = idx - 8192;
        int lane = t & 63, nt = (t >> 6) & 7, s = (t >> 9) & 1, layer = t >> 10;
        int q = lane >> 4, n = lane & 15;
        int col = nt * 16 + n;              // <64 -> w1, >=64 -> w2
        const float* W = (col < 64) ? (w1W + (size_t)layer * 64 * 64)
                                    : (w2W + (size_t)layer * 64 * 64);
        int c = col & 63;
        size_t o = (size_t)t * 8;
#pragma unroll
        for (int j = 0; j < 8; ++j) {
            float x = W[(size_t)(s * 32 + q * 8 + j) * 64 + c];
            unsigned short h, lo;
            split_hl(x, h, lo);
            nf_hi[o + j] = h; nf_lo[o + j] = lo;
        }
    }
}

// ---------------- MFMA GEMM, A staged in LDS (64-row blocks, R12-proven shape) --
// A fragments were the last per-lane scattered global access (16 different rows
// per quarter, 32B granules, latency-chained against MFMAs; R8: MfmaUtil 5.9%,
// VALUBusy 9.7%, HBM 15% — nothing busy => latency). The block's A-tile is
// contiguous in global -> stage with a coalesced 256-thread copy into padded
// LDS (+4 floats/row => 4-bank row shift, benign 2-way conflicts), then read
// fragments via ds_read_b128. W stays direct-from-global (R12 staging: null).
// C flushes through LDS reuse with coalesced 16B stores (R14: +10us).

__device__ __forceinline__ void mfma_steps_lds(const float* __restrict__ lda, int ldp,
                                               int nsteps,
                                               const unsigned short* __restrict__ wfh,
                                               const unsigned short* __restrict__ wfl,
                                               int lrow, int lq, int l,
                                               f32x4* acc) {
    for (int s = 0; s < nsteps; ++s) {
        const float* ap = lda + lrow * ldp + s * 32 + lq * 8;
        float4 a0 = *(const float4*)ap;
        float4 a1 = *(const float4*)(ap + 4);
        float xs[8] = {a0.x, a0.y, a0.z, a0.w, a1.x, a1.y, a1.z, a1.w};
        short8 ah, al;
#pragma unroll
        for (int c = 0; c < 8; ++c) {
            unsigned short h, lo;
            split_hl(xs[c], h, lo);
            ah[c] = (short)h; al[c] = (short)lo;
        }
#pragma unroll
        for (int nt = 0; nt < 8; ++nt) {
            size_t fo = ((size_t)(s * 8 + nt) * 64 + l) * 8;
            short8 wh = *(const short8*)(wfh + fo);
            short8 wl = *(const short8*)(wfl + fo);
            acc[nt] = __builtin_amdgcn_mfma_f32_16x16x32_bf16(ah, wh, acc[nt], 0, 0, 0);
            acc[nt] = __builtin_amdgcn_mfma_f32_16x16x32_bf16(ah, wl, acc[nt], 0, 0, 0);
            acc[nt] = __builtin_amdgcn_mfma_f32_16x16x32_bf16(al, wh, acc[nt], 0, 0, 0);
        }
    }
}

// Fused per-layer GEMM: blocks [0, MF_BLOCKS) GCN, [MF_BLOCKS, 2*MF_BLOCKS) GNA.
// Block = 64 rows, 4 waves x 16 rows. smem (33.8 KB) holds the staged A-tile
// during MFMA, then is reused for the C-tile flush.

__global__ __launch_bounds__(256) void gemm_both(
    const float* __restrict__ A0, const float* __restrict__ A1,
    const unsigned short* __restrict__ gfh, const unsigned short* __restrict__ gfl,
    const unsigned short* __restrict__ nfh, const unsigned short* __restrict__ nfl,
    const float* __restrict__ b1, const float* __restrict__ b2,
    const float* __restrict__ avec, const float* __restrict__ dinv,
    __half* __restrict__ h2, float* __restrict__ baseb,
    __half* __restrict__ ut, float* __restrict__ ub) {
    __shared__ __align__(16) char smem[33792];   // A: 64x132 f32 (GCN) / 64x68 (GNA); epilogue reuse
    int tid = threadIdx.x;
    int w  = tid >> 6;
    int l  = tid & 63;
    int lq = l >> 4;
    int ln = l & 15;
    bool isg = blockIdx.x >= MF_BLOCKS;
    int blk = isg ? (blockIdx.x - MF_BLOCKS) : blockIdx.x;
    int m0 = blk * 64;
    const float* A = isg ? A1 : A0;
    const int Kfull = isg ? 64 : 128;
    const int ldp   = isg ? 68 : 132;      // padded row stride (floats)
    float* lda = (float*)smem;

    // stage A tile: thread t -> row t>>2, quarter t&3 (coalesced, zero-fill tail)
    {
        int row = tid >> 2, q = tid & 3;
        int grow = m0 + row;
        int hw = Kfull >> 2;               // floats per quarter-row: 32 / 16
        float4* dst = (float4*)(lda + row * ldp + q * hw);
        int nv = hw >> 2;                  // float4s: 8 / 4
        if (grow < N_NODES) {
            const float4* src = (const float4*)(A + (size_t)grow * Kfull + q * hw);
            for (int i = 0; i < nv; ++i) dst[i] = src[i];
        } else {
            for (int i = 0; i < nv; ++i) dst[i] = make_float4(0.f, 0.f, 0.f, 0.f);
        }
    }
    __syncthreads();

    f32x4 acc[8];
#pragma unroll
    for (int i = 0; i < 8; ++i) acc[i] = (f32x4){0.f, 0.f, 0.f, 0.f};

    int lrow = w * 16 + ln;

    if (!isg) {
        mfma_steps_lds(lda, 132, 4, gfh, gfl, lrow, lq, l, acc);
        __syncthreads();                    // all A reads done; reuse smem for C
        __half* ldc = (__half*)smem;        // C [64][128] fp16 (16 KB)
        {
            float dv[4];
#pragma unroll
            for (int r = 0; r < 4; ++r) {
                int row = m0 + w * 16 + lq * 4 + r;
                dv[r] = (row < N_NODES) ? dinv[row] : 0.f;
            }
#pragma unroll
            for (int nt = 0; nt < 8; ++nt) {
                int col = nt * 16 + ln;
#pragma unroll
                for (int r = 0; r < 4; ++r) {
                    int lr = w * 16 + lq * 4 + r;
                    ldc[lr * 128 + col] = __float2half(acc[nt][r] * dv[r]);
                }
            }
        }
        __syncthreads();
        // flush: thread t -> row = t>>2, 64B segment = t&3 (4 x uint4)
        {
            int row = tid >> 2, seg = tid & 3;
            int grow = m0 + row;
            if (grow < N_NODES) {
                const uint4* src = (const uint4*)(ldc + row * 128 + seg * 32);
                uint4* dst = (uint4*)(h2 + (size_t)grow * 128 + seg * 32);
#pragma unroll
                for (int i = 0; i < 4; ++i) dst[i] = src[i];
            }
        }
    } else {
        mfma_steps_lds(lda, 68, 2, nfh, nfl, lrow, lq, l, acc);
        __syncthreads();                    // all A reads done; reuse smem
        float* ldf = (float*)smem;                      // base [64][64] f32 (16 KB)
        __half* ldh = (__half*)(smem + 16384);          // ut   [64][64] fp16 (8 KB)
        {
            // base = A1@W1 + b1 -> LDS
#pragma unroll
            for (int nt = 0; nt < 4; ++nt) {
                int col = nt * 16 + ln;
                float bb = b1[col];
#pragma unroll
                for (int r = 0; r < 4; ++r) {
                    int lr = w * 16 + lq * 4 + r;
                    ldf[lr * 64 + col] = acc[nt][r] + bb;
                }
            }
            // t = A1@W2 + b2; ta = t @ avec (row-reduce over 16 lanes)
            float pa[4] = {0.f, 0.f, 0.f, 0.f};
            float t2s[4][4];
#pragma unroll
            for (int nt = 4; nt < 8; ++nt) {
                int col = (nt - 4) * 16 + ln;
                float bb = b2[col];
                float av = avec[col];
#pragma unroll
                for (int r = 0; r < 4; ++r) {
                    float t2 = acc[nt][r] + bb;
                    t2s[nt - 4][r] = t2;
                    pa[r] += t2 * av;
                }
            }
#pragma unroll
            for (int r = 0; r < 4; ++r) {
                pa[r] += __shfl_xor(pa[r], 1);
                pa[r] += __shfl_xor(pa[r], 2);
                pa[r] += __shfl_xor(pa[r], 4);
                pa[r] += __shfl_xor(pa[r], 8);
            }
            float ur[4];
#pragma unroll
            for (int r = 0; r < 4; ++r) ur[r] = expf(-pa[r]);
            // ut = u * t (fp16) -> LDS
#pragma unroll
            for (int nt = 0; nt < 4; ++nt) {
                int col = nt * 16 + ln;
#pragma unroll
                for (int r = 0; r < 4; ++r) {
                    int lr = w * 16 + lq * 4 + r;
                    ldh[lr * 64 + col] = __float2half(t2s[nt][r] * ur[r]);
                }
            }
            if (ln == 0) {
#pragma unroll
                for (int r = 0; r < 4; ++r) {
                    int row = m0 + w * 16 + lq * 4 + r;
                    if (row < N_NODES) ub[row] = ur[r];
                }
            }
        }
        __syncthreads();
        // flush base (256B/row: 4 x uint4) + ut (128B/row: 2 x uint4)
        {
            int row = tid >> 2, seg = tid & 3;
            int grow = m0 + row;
            if (grow < N_NODES) {
                const uint4* src = (const uint4*)(ldf + row * 64 + seg * 16);
                uint4* dst = (uint4*)(baseb + (size_t)grow * 64 + seg * 16);
#pragma unroll
                for (int i = 0; i < 4; ++i) dst[i] = src[i];
                const uint4* srh = (const uint4*)(ldh + row * 64 + seg * 16);
                uint4* dsh = (uint4*)(ut + (size_t)grow * 64 + seg * 16);
#pragma unroll
                for (int i = 0; i < 2; ++i) dsh[i] = srh[i];
            }
        }
    }
}

// ---------------- GCN edge aggregation (TWO dsts per wave) ---------------------
// Each 32-lane half serves its own dst: 16 lanes x 16B cover the 256B fp16 row,
// 2 edge slots per half. Distributed epilogue: each lane covers 4 cols.

__global__ __launch_bounds__(256) void agg_gcn(const __half* __restrict__ h2,
                                               const int* __restrict__ ptrb,
                                               const int* __restrict__ eidx,
                                               const float* __restrict__ dinv,
                                               const float* __restrict__ bias,
                                               float* __restrict__ out,
                                               int apply_gelu) {
    int widx = (blockIdx.x * 256 + (int)threadIdx.x) >> 6;
    int lane = threadIdx.x & 63;
    int half = lane >> 5;
    int hl   = lane & 31;
    int dst  = widx * 2 + half;
    if (dst >= N_NODES) return;           // N even: both halves valid together
    int sub = hl >> 4;                    // 0..1 : edge slot within half
    int fl  = hl & 15;                    // 16 groups x 8 cols = 128
    int p0 = ptrb[dst], p1 = ptrb[dst + 1];
    float acc[8];
#pragma unroll
    for (int i = 0; i < 8; ++i) acc[i] = 0.f;
    for (int p = p0; p < p1; p += 32) {
        int nb = min(32, p1 - p);            // half-wave uniform
        int srcs = (hl < nb) ? eidx[p + hl] : 0;
        for (int eb = 0; eb < nb; eb += 16) { // uniform within half
            int   sv[8];
            float mk[8];
#pragma unroll
            for (int k = 0; k < 8; ++k) {
                int e = eb + sub + 2 * k;
                int c = half * 32 + min(e, nb - 1);
                sv[k] = __shfl(srcs, c);
                mk[k] = (e < nb) ? 1.f : 0.f;
            }
            float4 raw[8];
#pragma unroll
            for (int k = 0; k < 8; ++k)
                raw[k] = *(const float4*)(h2 + (size_t)sv[k] * 128 + fl * 8);
#pragma unroll
            for (int k = 0; k < 8; ++k) fma8h(raw[k], mk[k], acc);
        }
    }
    // reduce across the 2 subs (xor 16 stays within the half)
#pragma unroll
    for (int i = 0; i < 8; ++i) acc[i] += __shfl_xor(acc[i], 16);
    // distributed epilogue: lane covers cols c0 = fl*8 + 4*sub .. +3
    {
        float dd = dinv[dst];
        int c0 = fl * 8 + 4 * sub;
        float4 bb = *(const float4*)(bias + c0);
        float v0 = fmaf(dd, acc[4 * sub + 0], bb.x);
        float v1 = fmaf(dd, acc[4 * sub + 1], bb.y);
        float v2 = fmaf(dd, acc[4 * sub + 2], bb.z);
        float v3 = fmaf(dd, acc[4 * sub + 3], bb.w);
        if (apply_gelu) {
            v0 = gelu_f(v0); v1 = gelu_f(v1); v2 = gelu_f(v2); v3 = gelu_f(v3);
        }
        *(float4*)(out + (size_t)dst * 128 + c0) = make_float4(v0, v1, v2, v3);
    }
}

// ---------------- GNA edge aggregation (TWO dsts per wave) ---------------------
// Each 32-lane half serves its own dst: 8 lanes x 16B cover the 128B fp16 row,
// 4 edge slots per half. Distributed epilogue: each lane covers 2 cols.

__global__ __launch_bounds__(256) void gna_agg(const __half* __restrict__ ut,
                                               const float* __restrict__ ub,
                                               const int* __restrict__ ptrb,
                                               const int* __restrict__ eidx,
                                               const float* __restrict__ base,
                                               float* __restrict__ gout) {
    int widx = (blockIdx.x * 256 + (int)threadIdx.x) >> 6;
    int lane = threadIdx.x & 63;
    int half = lane >> 5;
    int hl   = lane & 31;
    int dst  = widx * 2 + half;
    if (dst >= N_NODES) return;
    int sub = hl >> 3;                    // 0..3 : edge slot within half
    int fl  = hl & 7;                     // 8 groups x 8 cols = 64
    int p0 = ptrb[dst], p1 = ptrb[dst + 1];
    float se = 0.f;
    float acc[8];
#pragma unroll
    for (int i = 0; i < 8; ++i) acc[i] = 0.f;
    for (int p = p0; p < p1; p += 32) {
        int nb = min(32, p1 - p);            // half-wave uniform
        int srcs = (hl < nb) ? eidx[p + hl] : 0;
        if (hl < nb) se += ub[srcs];         // L2-hot 200 KB table
        // 32 slots in one pass: e = sub + 4k, k = 0..7
        int   sv[8];
        float mk[8];
#pragma unroll
        for (int k = 0; k < 8; ++k) {
            int e = sub + 4 * k;
            int c = half * 32 + min(e, nb - 1);
            sv[k] = __shfl(srcs, c);
            mk[k] = (e < nb) ? 1.f : 0.f;
        }
        float4 raw[8];
#pragma unroll
        for (int k = 0; k < 8; ++k)
            raw[k] = *(const float4*)(ut + (size_t)sv[k] * 64 + fl * 8);
#pragma unroll
        for (int k = 0; k < 8; ++k) fma8h(raw[k], mk[k], acc);
    }
    // se reduce within half (offsets 1..16)
#pragma unroll
    for (int off = 1; off <= 16; off <<= 1) se += __shfl_xor(se, off);
    // acc reduce across the 4 subs (xor 8,16 stay within the half)
#pragma unroll
    for (int off = 8; off <= 16; off <<= 1)
#pragma unroll
        for (int i = 0; i < 8; ++i) acc[i] += __shfl_xor(acc[i], off);
    // distributed epilogue: lane covers cols c0 = fl*8 + 2*sub .. +1
    {
        float winv = __fdividef(1.0f, se + 1e-16f);
        int c0 = fl * 8 + 2 * sub;
        float2 bs = *(const float2*)(base + (size_t)dst * 64 + c0);
        float v0 = gelu_f(fmaf(acc[2 * sub + 0], winv, bs.x));
        float v1 = gelu_f(fmaf(acc[2 * sub + 1], winv, bs.y));
        *(float2*)(gout + (size_t)dst * 64 + c0) = make_float2(v0, v1);
    }
}

// ---------------- launch ----------------

extern "C" void kernel_launch(void* const* d_in, const int* in_sizes, int n_in,
                              void* d_out, int out_size, void* d_ws, size_t ws_size,
                              hipStream_t stream) {
    const float* x     = (const float*)d_in[0];
    const float* s     = (const float*)d_in[1];
    const int*   ei    = (const int*)d_in[2];
    const float* gcn_W = (const float*)d_in[3];
    const float* gcn_b = (const float*)d_in[4];
    const float* w1W   = (const float*)d_in[5];
    const float* w1b   = (const float*)d_in[6];
    const float* w2W   = (const float*)d_in[7];
    const float* w2b   = (const float*)d_in[8];
    const float* ga    = (const float*)d_in[9];

    float* h_out = (float*)d_out;                               // N x 128
    float* g_out = (float*)d_out + (size_t)N_NODES * 128;       // N x 64

    size_t off = 0;
    char* wsb = (char*)d_ws;
    auto take = [&](size_t bytes) {
        void* p = wsb + off;
        off = (off + bytes + 255) & ~(size_t)255;
        return p;
    };
    int*    cnt     = (int*)take((size_t)N_NODES * 4);
    int*    ptrb    = (int*)take((size_t)(N_NODES + 1) * 4);
    int*    aux     = (int*)take((size_t)ET * 4);
    float*  dinv    = (float*)take((size_t)N_NODES * 4);
    int*    eidx    = (int*)take((size_t)ET * 4);
    __half* h2      = (__half*)take((size_t)N_NODES * 128 * 2);
    __half* utbuf   = (__half*)take((size_t)N_NODES * 64 * 2);
    float*  basebuf = (float*)take((size_t)N_NODES * 64 * 4);
    float*  ubuf    = (float*)take((size_t)N_NODES * 4);
    int*    bsum    = (int*)take((size_t)NB_SCAN * 4);
    unsigned short* gf_hi = (unsigned short*)take((size_t)8192 * 8 * 2);
    unsigned short* gf_lo = (unsigned short*)take((size_t)8192 * 8 * 2);
    unsigned short* nf_hi = (unsigned short*)take((size_t)4096 * 8 * 2);
    unsigned short* nf_lo = (unsigned short*)take((size_t)4096 * 8 * 2);
    (void)ws_size; (void)in_sizes; (void)n_in; (void)out_size;

    const int* erow = ei;
    const int* ecol = ei + E_EDGES;

    hipMemsetAsync(cnt, 0, (size_t)N_NODES * 4, stream);

    int ge = (ET + 255) / 256;
    count_pos<<<ge, 256, 0, stream>>>(ecol, cnt, aux);
    scan_part1<<<NB_SCAN, 256, 0, stream>>>(cnt, bsum);
    scan_part3<<<NB_SCAN, 256, 0, stream>>>(cnt, bsum, ptrb, dinv);
    bucket<<<ge, 256, 0, stream>>>(erow, ecol, aux, ptrb, eidx);
    prep_w<<<48, 256, 0, stream>>>(gcn_W, w1W, w2W, gf_hi, gf_lo, nf_hi, nf_lo);

    const float* hin = x;
    const float* gin = s;
    for (int l = 0; l < L_LAYERS; ++l) {
        gemm_both<<<2 * MF_BLOCKS, 256, 0, stream>>>(
            hin, gin,
            gf_hi + (size_t)l * 4 * 8 * 64 * 8, gf_lo + (size_t)l * 4 * 8 * 64 * 8,
            nf_hi + (size_t)l * 2 * 8 * 64 * 8, nf_lo + (size_t)l * 2 * 8 * 64 * 8,
            w1b + (size_t)l * 64, w2b + (size_t)l * 64, ga + (size_t)l * 64, dinv,
            h2, basebuf, utbuf, ubuf);
        agg_gcn<<<AGG_BLOCKS, 256, 0, stream>>>(
            h2, ptrb, eidx, dinv, gcn_b + (size_t)l * 128, h_out,
            (l < L_LAYERS - 1) ? 1 : 0);
        gna_agg<<<AGG_BLOCKS, 256, 0, stream>>>(
            utbuf, ubuf, ptrb, eidx, basebuf, g_out);
        hin = h_out;
        gin = g_out;
    }
}